// Round 10
// baseline (129.034 us; speedup 1.0000x reference)
//
#include <hip/hip_runtime.h>
#include <math.h>

#define D 256
#define H2 512
#define HEADS 8
#define L 25
#define GH 64
#define GW 64
#define NN 4096
#define EPS 1e-5f
#define SCALE 0.17677669529663687f  // 1/sqrt(32)
#define NND 1048576                 // NN*D
#define ROWS 8                      // rows per fused block
#define UN 60                       // union rows: 5 x 12

typedef __attribute__((ext_vector_type(8))) short short8;
typedef __attribute__((ext_vector_type(4))) float f32x4;

__device__ __forceinline__ bool act_at(const int* __restrict__ active, int h, int w) {
    if (h < 0 || h >= GH || w < 0 || w >= GW) return false;
    if (h == 2 && w == 2) return false;   // ap.at[:, center, center].set(False) quirk
    return active[h * GW + w] != 0;
}

__device__ __forceinline__ unsigned short f2b(float f) {
    unsigned u = __float_as_uint(f);
    u += 0x7fffu + ((u >> 16) & 1u);      // RNE
    return (unsigned short)(u >> 16);
}
__device__ __forceinline__ float b2f(short v) {
    return __uint_as_float(((unsigned)(unsigned short)v) << 16);
}

// ---------------- prep: weight transposes (f32->bf16) + bias rows ----------------
__global__ __launch_bounds__(256)
void prep_kernel(const float* __restrict__ attn_w, const float* __restrict__ pattn_w,
                 const float* __restrict__ ff_w1, const float* __restrict__ ff_w2,
                 const float* __restrict__ pattn_b,
                 unsigned short* __restrict__ wB,
                 unsigned short* __restrict__ k2bias, unsigned short* __restrict__ v2bias) {
    const int tid = threadIdx.x;
    const int bid = blockIdx.x;
    if (bid < 192) {
        __shared__ float tile[64][65];
        const float* src; unsigned short* dst;
        int i0, n0, srcLen, dstLen;
        if (bid < 128) {
            int mat = bid >> 4, t16 = bid & 15;
            i0 = (t16 >> 2) * 64; n0 = (t16 & 3) * 64;
            src = (mat < 4) ? (attn_w + mat * 65536) : (pattn_w + (mat - 4) * 65536);
            dst = wB + mat * 65536;
            srcLen = 256; dstLen = 256;
        } else if (bid < 160) {
            int t = bid - 128;
            i0 = (t >> 3) * 64; n0 = (t & 7) * 64;
            src = ff_w1; dst = wB + 524288;      // W1T: [512][256]
            srcLen = 512; dstLen = 256;
        } else {
            int t = bid - 160;
            i0 = (t >> 2) * 64; n0 = (t & 3) * 64;
            src = ff_w2; dst = wB + 655360;      // W2T: [256][512]
            srcLen = 256; dstLen = 512;
        }
        int c = tid & 63, r4 = tid >> 6;
        for (int rr = 0; rr < 64; rr += 4)
            tile[rr + r4][c] = src[(size_t)(i0 + rr + r4) * srcLen + n0 + c];
        __syncthreads();
        for (int rr = 0; rr < 64; rr += 4) {
            int r = rr + r4;
            dst[(size_t)(n0 + r) * dstLen + i0 + c] = f2b(tile[c][r]);
        }
    } else {
        // bias rows for K2/V2 (row 4096)
        if (tid < 256) {
            k2bias[tid] = f2b(pattn_b[256 + tid]);
            v2bias[tid] = f2b(pattn_b[512 + tid]);
        }
    }
}

// ---------------- proj: 5 GEMM streams, A read f32 + inline mask/cvt ----------------
__global__ __launch_bounds__(256)
void proj_gemm(const float* __restrict__ x, const float* __restrict__ mem,
               const int* __restrict__ active,
               const unsigned short* __restrict__ wB,
               const float* __restrict__ attn_b, const float* __restrict__ pattn_b,
               unsigned short* __restrict__ q1b, unsigned short* __restrict__ k1b,
               unsigned short* __restrict__ v1b, unsigned short* __restrict__ k2b,
               unsigned short* __restrict__ v2b) {
    const int s  = blockIdx.y >> 2;       // 0:Q1 1:K1 2:V1 3:K2 4:V2
    const int n0 = (blockIdx.y & 3) * 64;
    const float* Asrc = (s < 3) ? x : mem;
    const bool useMask = (s < 3);
    const int wtIdx = (s < 3) ? s : (s + 2);            // K2->5, V2->6
    const unsigned short* WT = wB + (size_t)wtIdx * 65536;
    const float* bias = (s < 3) ? (attn_b + s * 256) : (pattn_b + (s - 2) * 256);
    unsigned short* outB;
    switch (s) { case 0: outB = q1b; break; case 1: outB = k1b; break;
                 case 2: outB = v1b; break; case 3: outB = k2b; break;
                 default: outB = v2b; }

    const int tid = threadIdx.x;
    const int wave = tid >> 6, lane = tid & 63;
    const int m0 = blockIdx.x * 64 + wave * 16;
    const int lr = lane & 15;
    const int lk = (lane >> 4) << 3;
    const int arowIdx = m0 + lr;
    const bool rowAct = !useMask || act_at(active, arowIdx >> 6, arowIdx & 63);

    f32x4 acc[4] = {};
    const float* arow = Asrc + (size_t)arowIdx * 256 + lk;
    const unsigned short* brow = WT + (size_t)(n0 + lr) * 256 + lk;
    #pragma unroll
    for (int kk = 0; kk < 256; kk += 32) {
        float4 a0 = *(const float4*)(arow + kk);
        float4 a1 = *(const float4*)(arow + kk + 4);
        short8 a;
        a[0] = rowAct ? (short)f2b(a0.x) : (short)0;
        a[1] = rowAct ? (short)f2b(a0.y) : (short)0;
        a[2] = rowAct ? (short)f2b(a0.z) : (short)0;
        a[3] = rowAct ? (short)f2b(a0.w) : (short)0;
        a[4] = rowAct ? (short)f2b(a1.x) : (short)0;
        a[5] = rowAct ? (short)f2b(a1.y) : (short)0;
        a[6] = rowAct ? (short)f2b(a1.z) : (short)0;
        a[7] = rowAct ? (short)f2b(a1.w) : (short)0;
        #pragma unroll
        for (int nf = 0; nf < 4; ++nf) {
            short8 b = *(const short8*)(brow + (size_t)nf * 16 * 256 + kk);
            acc[nf] = __builtin_amdgcn_mfma_f32_16x16x32_bf16(a, b, acc[nf], 0, 0, 0);
        }
    }
    const int rbase = m0 + ((lane >> 4) << 2);
    #pragma unroll
    for (int nf = 0; nf < 4; ++nf) {
        int c = n0 + nf * 16 + lr;
        float bc = bias[c];
        #pragma unroll
        for (int jj = 0; jj < 4; ++jj)
            outB[(size_t)(rbase + jj) * 256 + c] = f2b(acc[nf][jj] + bc);
    }
}

// ---------------- LDS layout (8-row fused) ----------------
#define KV_OFF   0            // union: 60 rows x 256 bf16 = 30720
#define ACT_OFF  30720        // 64
#define WGT_OFF  30784        // [8][8][25] f32 = 6400 -> ends 37184
#define REDA_OFF 37184        // [16][4] f32 = 256
#define REDB_OFF 37440        // 256
#define STAT_OFF 37696        // [16][2] f32 = 128
#define SMEM_SZ  37824
// aliases into [0, 37184):
#define T1B_OFF  0            // [16][264] bf16 = 8448  (T1 / T2 staging / T3)
#define SB_OFF   8448         // [16][264] bf16 = 8448  (S / S2)
#define HB_OFF   16896        // [16][520] bf16 = 16640 (FF hidden; overlaps dead wgt)

__device__ __forceinline__ void load_union60(const unsigned short* __restrict__ base,
                                             int h, int w0, int fallback,
                                             unsigned short (*kvU)[256], int tid) {
    for (int c = tid; c < UN * 32; c += 256) {
        int u = c >> 5, part = c & 31;
        int r = u / 12, cc = u - r * 12;
        int hh = h - 2 + r, ww = w0 - 2 + cc;
        bool ib = ((unsigned)hh < GH) && ((unsigned)ww < GW);
        int row = ib ? ((hh << 6) | ww) : fallback;
        *(uint4*)&kvU[u][part * 8] = *(const uint4*)(base + (size_t)row * 256 + part * 8);
    }
}

// ---------------- fused: attn1 + Wo1+LN0 + Wq2 + attn2 + Wo2+LN2 + FF1 + FF2+LN1 ----
__global__ __launch_bounds__(256)
void fused_kernel(const int* __restrict__ active, const float* __restrict__ x,
                  const unsigned short* __restrict__ wB,
                  const float* __restrict__ attn_b, const float* __restrict__ pattn_b,
                  const float* __restrict__ ff_b1, const float* __restrict__ ff_b2,
                  const float* __restrict__ ln_g, const float* __restrict__ ln_b,
                  const unsigned short* __restrict__ q1b,
                  const unsigned short* __restrict__ k1b,
                  const unsigned short* __restrict__ v1b,
                  const unsigned short* __restrict__ k2b,
                  const unsigned short* __restrict__ v2b,
                  float* __restrict__ out) {
    const int tid = threadIdx.x;              // 256 threads, 4 waves
    const int wv = tid >> 6, lane = tid & 63;
    const int lr = lane & 15, qi = lane >> 4;
    const int half = lane >> 5, lam = lane & 31;
    const int m = wv * 2 + half;              // node 0..7
    const int bid = ((blockIdx.x & 7) << 6) | (blockIdx.x >> 3);   // XCD-chunked
    const int n0 = bid * ROWS;
    const int h = n0 >> 6, w0 = n0 & 63;

    __shared__ __align__(16) char smem[SMEM_SZ];
    unsigned short (*kvU)[256] = (unsigned short(*)[256])(smem + KV_OFF);
    unsigned char* actU        = (unsigned char*)(smem + ACT_OFF);
    float (*wgt)[8][25]        = (float(*)[8][25])(smem + WGT_OFF);
    float (*redA)[4]           = (float(*)[4])(smem + REDA_OFF);
    float (*redB)[4]           = (float(*)[4])(smem + REDB_OFF);
    float (*stats)[2]          = (float(*)[2])(smem + STAT_OFF);
    unsigned short (*T1b)[264] = (unsigned short(*)[264])(smem + T1B_OFF);
    unsigned short (*Sb)[264]  = (unsigned short(*)[264])(smem + SB_OFF);
    unsigned short (*Hb)[520]  = (unsigned short(*)[520])(smem + HB_OFF);

    // ---- masks + K1 union ----
    if (tid < UN) {
        int r = tid / 12;
        int hh = h - 2 + r, ww = w0 - 2 + (tid - r * 12);
        actU[tid] = act_at(active, hh, ww) ? 1 : 0;
    }
    load_union60(k1b, h, w0, 0, kvU, tid);
    __syncthreads();

    // ---- attn1 scores (half-wave per node) ----
    {
        float q[8];
        short8 qv = *(const short8*)(q1b + (size_t)(n0 + m) * 256 + lam * 8);
        #pragma unroll
        for (int j = 0; j < 8; ++j) q[j] = b2f(qv[j]);
        #pragma unroll 5
        for (int l = 0; l < L; ++l) {
            int u = (l / 5) * 12 + m + (l % 5);
            short8 kv = *(const short8*)&kvU[u][lam * 8];
            float p = q[0] * b2f(kv[0]);
            #pragma unroll
            for (int j = 1; j < 8; ++j) p = fmaf(q[j], b2f(kv[j]), p);
            p += __shfl_xor(p, 1); p += __shfl_xor(p, 2);
            float sv = actU[u] ? p * SCALE : -1e30f;
            if ((lam & 3) == 0) wgt[m][lam >> 2][l] = sv;
        }
    }
    __syncthreads();
    if (tid < 64) {
        int mm = tid >> 3, hd = tid & 7;
        float mx = -1e30f;
        for (int l = 0; l < L; ++l) mx = fmaxf(mx, wgt[mm][hd][l]);
        float sum = 0.0f;
        for (int l = 0; l < L; ++l) { float e = expf(wgt[mm][hd][l] - mx); wgt[mm][hd][l] = e; sum += e; }
        float inv = 1.0f / sum;
        for (int l = 0; l < L; ++l) wgt[mm][hd][l] *= inv;
    }
    __syncthreads();
    load_union60(v1b, h, w0, 0, kvU, tid);
    __syncthreads();
    // ---- PV1 -> T1b ----
    {
        float o[8] = {0.f,0.f,0.f,0.f,0.f,0.f,0.f,0.f};
        #pragma unroll 5
        for (int l = 0; l < L; ++l) {
            int u = (l / 5) * 12 + m + (l % 5);
            if (actU[u]) {
                float wt = wgt[m][lam >> 2][l];
                short8 v8 = *(const short8*)&kvU[u][lam * 8];
                #pragma unroll
                for (int j = 0; j < 8; ++j) o[j] = fmaf(wt, b2f(v8[j]), o[j]);
            }
        }
        __syncthreads();
        unsigned short u8[8];
        #pragma unroll
        for (int j = 0; j < 8; ++j) u8[j] = f2b(o[j]);
        *(uint4*)&T1b[m][lam * 8] = *(uint4*)u8;
    }
    __syncthreads();

    // ---- Wo1 + bias + resid(x) + LN0 -> sreg + Sb ----
    float sreg[4][4];
    {
        const unsigned short* Wo1T = wB + 3 * 65536;
        f32x4 acc[4] = {};
        #pragma unroll
        for (int kk = 0; kk < 256; kk += 32) {
            short8 a = *(const short8*)&T1b[lr][qi * 8 + kk];
            #pragma unroll
            for (int nf = 0; nf < 4; ++nf) {
                short8 b = *(const short8*)(Wo1T + (size_t)(wv * 64 + nf * 16 + lr) * 256 + qi * 8 + kk);
                acc[nf] = __builtin_amdgcn_mfma_f32_16x16x32_bf16(a, b, acc[nf], 0, 0, 0);
            }
        }
        float v[4][4], s1[4] = {0.f,0.f,0.f,0.f}, s2[4] = {0.f,0.f,0.f,0.f};
        #pragma unroll
        for (int nf = 0; nf < 4; ++nf) {
            int c = wv * 64 + nf * 16 + lr;
            float bc = attn_b[768 + c];
            #pragma unroll
            for (int jj = 0; jj < 4; ++jj) {
                int ridx = qi * 4 + jj;
                float xr = x[(size_t)(n0 + (ridx & 7)) * D + c];
                float vv = acc[nf][jj] + bc + xr;
                v[nf][jj] = vv; s1[jj] += vv; s2[jj] += vv * vv;
            }
        }
        #pragma unroll
        for (int jj = 0; jj < 4; ++jj) {
            #pragma unroll
            for (int off = 1; off < 16; off <<= 1) {
                s1[jj] += __shfl_xor(s1[jj], off);
                s2[jj] += __shfl_xor(s2[jj], off);
            }
        }
        if (lr == 0) {
            #pragma unroll
            for (int jj = 0; jj < 4; ++jj) { redA[qi*4+jj][wv] = s1[jj]; redB[qi*4+jj][wv] = s2[jj]; }
        }
        __syncthreads();
        if (tid < 16) {
            float a1 = redA[tid][0]+redA[tid][1]+redA[tid][2]+redA[tid][3];
            float a2 = redB[tid][0]+redB[tid][1]+redB[tid][2]+redB[tid][3];
            float mu = a1 * (1.0f / D);
            float var = a2 * (1.0f / D) - mu * mu;
            stats[tid][0] = mu; stats[tid][1] = rsqrtf(var + EPS);
        }
        __syncthreads();
        #pragma unroll
        for (int nf = 0; nf < 4; ++nf) {
            int c = wv * 64 + nf * 16 + lr;
            float gg = ln_g[c], bb = ln_b[c];
            #pragma unroll
            for (int jj = 0; jj < 4; ++jj) {
                int ridx = qi * 4 + jj;
                float ov = (v[nf][jj] - stats[ridx][0]) * stats[ridx][1] * gg + bb;
                sreg[nf][jj] = ov;
                Sb[ridx][c] = f2b(ov);
            }
        }
    }
    __syncthreads();

    // ---- Wq2 -> T2 staged in T1b ----
    {
        const unsigned short* Wq2T = wB + 4 * 65536;
        f32x4 acc[4] = {};
        #pragma unroll
        for (int kk = 0; kk < 256; kk += 32) {
            short8 a = *(const short8*)&Sb[lr][qi * 8 + kk];
            #pragma unroll
            for (int nf = 0; nf < 4; ++nf) {
                short8 b = *(const short8*)(Wq2T + (size_t)(wv * 64 + nf * 16 + lr) * 256 + qi * 8 + kk);
                acc[nf] = __builtin_amdgcn_mfma_f32_16x16x32_bf16(a, b, acc[nf], 0, 0, 0);
            }
        }
        __syncthreads();
        #pragma unroll
        for (int nf = 0; nf < 4; ++nf) {
            int c = wv * 64 + nf * 16 + lr;
            float bc = pattn_b[c];
            #pragma unroll
            for (int jj = 0; jj < 4; ++jj)
                T1b[qi * 4 + jj][c] = f2b(acc[nf][jj] + bc);
        }
    }
    __syncthreads();

    // ---- q2 to regs, then K2 union ----
    float q2[8];
    {
        short8 qv = *(const short8*)&T1b[m][lam * 8];
        #pragma unroll
        for (int j = 0; j < 8; ++j) q2[j] = b2f(qv[j]);
    }
    __syncthreads();
    load_union60(k2b, h, w0, NN, kvU, tid);   // OOB -> bias row
    __syncthreads();

    // ---- attn2 scores ----
    #pragma unroll 5
    for (int l = 0; l < L; ++l) {
        int u = (l / 5) * 12 + m + (l % 5);
        short8 kv = *(const short8*)&kvU[u][lam * 8];
        float p = q2[0] * b2f(kv[0]);
        #pragma unroll
        for (int j = 1; j < 8; ++j) p = fmaf(q2[j], b2f(kv[j]), p);
        p += __shfl_xor(p, 1); p += __shfl_xor(p, 2);
        if ((lam & 3) == 0) wgt[m][lam >> 2][l] = p * SCALE;
    }
    __syncthreads();
    if (tid < 64) {
        int mm = tid >> 3, hd = tid & 7;
        float mx = -1e30f;
        for (int l = 0; l < L; ++l) mx = fmaxf(mx, wgt[mm][hd][l]);
        float sum = 0.0f;
        for (int l = 0; l < L; ++l) { float e = expf(wgt[mm][hd][l] - mx); wgt[mm][hd][l] = e; sum += e; }
        float inv = 1.0f / sum;
        for (int l = 0; l < L; ++l) wgt[mm][hd][l] *= inv;
    }
    __syncthreads();
    load_union60(v2b, h, w0, NN, kvU, tid);
    __syncthreads();
    // ---- PV2 -> T3b ----
    {
        float o[8] = {0.f,0.f,0.f,0.f,0.f,0.f,0.f,0.f};
        #pragma unroll 5
        for (int l = 0; l < L; ++l) {
            int u = (l / 5) * 12 + m + (l % 5);
            float wt = wgt[m][lam >> 2][l];
            short8 v8 = *(const short8*)&kvU[u][lam * 8];
            #pragma unroll
            for (int j = 0; j < 8; ++j) o[j] = fmaf(wt, b2f(v8[j]), o[j]);
        }
        __syncthreads();
        unsigned short u8[8];
        #pragma unroll
        for (int j = 0; j < 8; ++j) u8[j] = f2b(o[j]);
        *(uint4*)&T1b[m][lam * 8] = *(uint4*)u8;
    }
    __syncthreads();

    // ---- Wo2 + bias + resid(sreg) + LN2 -> s2reg + Sb ----
    float s2reg[4][4];
    {
        const unsigned short* Wo2T = wB + 7 * 65536;
        f32x4 acc[4] = {};
        #pragma unroll
        for (int kk = 0; kk < 256; kk += 32) {
            short8 a = *(const short8*)&T1b[lr][qi * 8 + kk];
            #pragma unroll
            for (int nf = 0; nf < 4; ++nf) {
                short8 b = *(const short8*)(Wo2T + (size_t)(wv * 64 + nf * 16 + lr) * 256 + qi * 8 + kk);
                acc[nf] = __builtin_amdgcn_mfma_f32_16x16x32_bf16(a, b, acc[nf], 0, 0, 0);
            }
        }
        float v[4][4], s1[4] = {0.f,0.f,0.f,0.f}, s2[4] = {0.f,0.f,0.f,0.f};
        #pragma unroll
        for (int nf = 0; nf < 4; ++nf) {
            int c = wv * 64 + nf * 16 + lr;
            float bc = pattn_b[768 + c];
            #pragma unroll
            for (int jj = 0; jj < 4; ++jj) {
                float vv = acc[nf][jj] + bc + sreg[nf][jj];
                v[nf][jj] = vv; s1[jj] += vv; s2[jj] += vv * vv;
            }
        }
        #pragma unroll
        for (int jj = 0; jj < 4; ++jj) {
            #pragma unroll
            for (int off = 1; off < 16; off <<= 1) {
                s1[jj] += __shfl_xor(s1[jj], off);
                s2[jj] += __shfl_xor(s2[jj], off);
            }
        }
        if (lr == 0) {
            #pragma unroll
            for (int jj = 0; jj < 4; ++jj) { redA[qi*4+jj][wv] = s1[jj]; redB[qi*4+jj][wv] = s2[jj]; }
        }
        __syncthreads();
        if (tid < 16) {
            float a1 = redA[tid][0]+redA[tid][1]+redA[tid][2]+redA[tid][3];
            float a2 = redB[tid][0]+redB[tid][1]+redB[tid][2]+redB[tid][3];
            float mu = a1 * (1.0f / D);
            float var = a2 * (1.0f / D) - mu * mu;
            stats[tid][0] = mu; stats[tid][1] = rsqrtf(var + EPS);
        }
        __syncthreads();
        #pragma unroll
        for (int nf = 0; nf < 4; ++nf) {
            int c = wv * 64 + nf * 16 + lr;
            float gg = ln_g[512 + c], bb = ln_b[512 + c];
            #pragma unroll
            for (int jj = 0; jj < 4; ++jj) {
                int ridx = qi * 4 + jj;
                float ov = (v[nf][jj] - stats[ridx][0]) * stats[ridx][1] * gg + bb;
                s2reg[nf][jj] = ov;
                Sb[ridx][c] = f2b(ov);
            }
        }
    }
    __syncthreads();

    // ---- FF1 -> Hb ----
    {
        const unsigned short* W1T = wB + 524288;
        f32x4 acc[8] = {};
        #pragma unroll
        for (int kk = 0; kk < 256; kk += 32) {
            short8 a = *(const short8*)&Sb[lr][qi * 8 + kk];
            #pragma unroll
            for (int nf = 0; nf < 8; ++nf) {
                short8 b = *(const short8*)(W1T + (size_t)(wv * 128 + nf * 16 + lr) * 256 + qi * 8 + kk);
                acc[nf] = __builtin_amdgcn_mfma_f32_16x16x32_bf16(a, b, acc[nf], 0, 0, 0);
            }
        }
        #pragma unroll
        for (int nf = 0; nf < 8; ++nf) {
            int c = wv * 128 + nf * 16 + lr;
            float bc = ff_b1[c];
            #pragma unroll
            for (int jj = 0; jj < 4; ++jj)
                Hb[qi * 4 + jj][c] = f2b(fmaxf(acc[nf][jj] + bc, 0.0f));
        }
    }
    __syncthreads();

    // ---- FF2 (K=512) + resid(s2reg) + LN1 + mask -> out ----
    {
        const unsigned short* W2T = wB + 655360;
        f32x4 acc[4] = {};
        #pragma unroll
        for (int kk = 0; kk < 512; kk += 32) {
            short8 a = *(const short8*)&Hb[lr][qi * 8 + kk];
            #pragma unroll
            for (int nf = 0; nf < 4; ++nf) {
                short8 b = *(const short8*)(W2T + (size_t)(wv * 64 + nf * 16 + lr) * 512 + qi * 8 + kk);
                acc[nf] = __builtin_amdgcn_mfma_f32_16x16x32_bf16(a, b, acc[nf], 0, 0, 0);
            }
        }
        float v[4][4], s1[4] = {0.f,0.f,0.f,0.f}, s2[4] = {0.f,0.f,0.f,0.f};
        #pragma unroll
        for (int nf = 0; nf < 4; ++nf) {
            int c = wv * 64 + nf * 16 + lr;
            float bc = ff_b2[c];
            #pragma unroll
            for (int jj = 0; jj < 4; ++jj) {
                float vv = acc[nf][jj] + bc + s2reg[nf][jj];
                v[nf][jj] = vv; s1[jj] += vv; s2[jj] += vv * vv;
            }
        }
        #pragma unroll
        for (int jj = 0; jj < 4; ++jj) {
            #pragma unroll
            for (int off = 1; off < 16; off <<= 1) {
                s1[jj] += __shfl_xor(s1[jj], off);
                s2[jj] += __shfl_xor(s2[jj], off);
            }
        }
        if (lr == 0) {
            #pragma unroll
            for (int jj = 0; jj < 4; ++jj) { redA[qi*4+jj][wv] = s1[jj]; redB[qi*4+jj][wv] = s2[jj]; }
        }
        __syncthreads();
        if (tid < 16) {
            float a1 = redA[tid][0]+redA[tid][1]+redA[tid][2]+redA[tid][3];
            float a2 = redB[tid][0]+redB[tid][1]+redB[tid][2]+redB[tid][3];
            float mu = a1 * (1.0f / D);
            float var = a2 * (1.0f / D) - mu * mu;
            stats[tid][0] = mu; stats[tid][1] = rsqrtf(var + EPS);
        }
        __syncthreads();
        #pragma unroll
        for (int nf = 0; nf < 4; ++nf) {
            int c = wv * 64 + nf * 16 + lr;
            float gg = ln_g[256 + c], bb = ln_b[256 + c];
            #pragma unroll
            for (int jj = 0; jj < 4; ++jj) {
                int ridx = qi * 4 + jj;
                if (ridx < ROWS) {
                    int row = n0 + ridx;
                    bool a = act_at(active, row >> 6, row & 63);
                    float ov = (v[nf][jj] - stats[ridx][0]) * stats[ridx][1] * gg + bb;
                    out[(size_t)row * D + c] = a ? ov : 0.0f;
                }
            }
        }
        if (tid < ROWS) {
            int row = n0 + tid;
            out[(size_t)NND + row] = act_at(active, row >> 6, row & 63) ? 1.0f : 0.0f;
        }
    }
}

extern "C" void kernel_launch(void* const* d_in, const int* in_sizes, int n_in,
                              void* d_out, int out_size, void* d_ws, size_t ws_size,
                              hipStream_t stream) {
    const float* x       = (const float*)d_in[0];
    const float* memory  = (const float*)d_in[1];
    const int*   active  = (const int*)d_in[2];
    const float* attn_w  = (const float*)d_in[3];
    const float* attn_b  = (const float*)d_in[4];
    const float* pattn_w = (const float*)d_in[5];
    const float* pattn_b = (const float*)d_in[6];
    const float* ff_w1   = (const float*)d_in[7];
    const float* ff_b1   = (const float*)d_in[8];
    const float* ff_w2   = (const float*)d_in[9];
    const float* ff_b2   = (const float*)d_in[10];
    const float* ln_g    = (const float*)d_in[11];
    const float* ln_b    = (const float*)d_in[12];
    float* out = (float*)d_out;

    unsigned short* wsb = (unsigned short*)d_ws;
    unsigned short* wB   = wsb;                                 // 786432 shorts
    unsigned short* q1b  = wB + 786432;
    unsigned short* k1b  = q1b + (size_t)NND;
    unsigned short* v1b  = k1b + (size_t)NND;
    unsigned short* k2b  = v1b + (size_t)NND;                   // 4097 rows
    unsigned short* v2b  = k2b + (size_t)NND + 256;             // 4097 rows

    hipLaunchKernelGGL(prep_kernel, dim3(193), dim3(256), 0, stream,
                       attn_w, pattn_w, ff_w1, ff_w2, pattn_b,
                       wB, k2b + (size_t)NND, v2b + (size_t)NND);
    hipLaunchKernelGGL(proj_gemm, dim3(64, 20), dim3(256), 0, stream,
                       x, memory, active, wB, attn_b, pattn_b,
                       q1b, k1b, v1b, k2b, v2b);
    hipLaunchKernelGGL(fused_kernel, dim3(512), dim3(256), 0, stream,
                       active, x, wB, attn_b, pattn_b, ff_b1, ff_b2, ln_g, ln_b,
                       q1b, k1b, v1b, k2b, v2b, out);
}

// Round 11
// 102.166 us; speedup vs baseline: 1.2630x; 1.2630x over previous
//
#include <hip/hip_runtime.h>
#include <math.h>

#define D 256
#define H2 512
#define HEADS 8
#define L 25
#define GH 64
#define GW 64
#define NN 4096
#define EPS 1e-5f
#define SCALE 0.17677669529663687f  // 1/sqrt(32)
#define NND 1048576                 // NN*D

typedef __attribute__((ext_vector_type(8))) short short8;
typedef __attribute__((ext_vector_type(4))) float f32x4;

__device__ __forceinline__ bool act_at(const int* __restrict__ active, int h, int w) {
    if (h < 0 || h >= GH || w < 0 || w >= GW) return false;
    if (h == 2 && w == 2) return false;   // ap.at[:, center, center].set(False) quirk
    return active[h * GW + w] != 0;
}

__device__ __forceinline__ unsigned short f2b(float f) {
    unsigned u = __float_as_uint(f);
    u += 0x7fffu + ((u >> 16) & 1u);      // RNE
    return (unsigned short)(u >> 16);
}
__device__ __forceinline__ float b2f(short v) {
    return __uint_as_float(((unsigned)(unsigned short)v) << 16);
}

// ---------------- prep: weight transposes (f32->bf16) + bias rows ----------------
__global__ __launch_bounds__(256)
void prep_kernel(const float* __restrict__ attn_w, const float* __restrict__ pattn_w,
                 const float* __restrict__ ff_w1, const float* __restrict__ ff_w2,
                 const float* __restrict__ pattn_b,
                 unsigned short* __restrict__ wB,
                 unsigned short* __restrict__ k2bias, unsigned short* __restrict__ v2bias) {
    const int tid = threadIdx.x;
    const int bid = blockIdx.x;
    if (bid < 192) {
        __shared__ float tile[64][65];
        const float* src; unsigned short* dst;
        int i0, n0, srcLen, dstLen;
        if (bid < 128) {
            int mat = bid >> 4, t16 = bid & 15;
            i0 = (t16 >> 2) * 64; n0 = (t16 & 3) * 64;
            src = (mat < 4) ? (attn_w + mat * 65536) : (pattn_w + (mat - 4) * 65536);
            dst = wB + mat * 65536;
            srcLen = 256; dstLen = 256;
        } else if (bid < 160) {
            int t = bid - 128;
            i0 = (t >> 3) * 64; n0 = (t & 7) * 64;
            src = ff_w1; dst = wB + 524288;      // W1T: [512][256]
            srcLen = 512; dstLen = 256;
        } else {
            int t = bid - 160;
            i0 = (t >> 2) * 64; n0 = (t & 3) * 64;
            src = ff_w2; dst = wB + 655360;      // W2T: [256][512]
            srcLen = 256; dstLen = 512;
        }
        int c = tid & 63, r4 = tid >> 6;
        for (int rr = 0; rr < 64; rr += 4)
            tile[rr + r4][c] = src[(size_t)(i0 + rr + r4) * srcLen + n0 + c];
        __syncthreads();
        for (int rr = 0; rr < 64; rr += 4) {
            int r = rr + r4;
            dst[(size_t)(n0 + r) * dstLen + i0 + c] = f2b(tile[c][r]);
        }
    } else {
        if (tid < 256) {
            k2bias[tid] = f2b(pattn_b[256 + tid]);
            v2bias[tid] = f2b(pattn_b[512 + tid]);
        }
    }
}

// ---------------- proj: 5 GEMM streams, A read f32 + inline mask/cvt ----------------
__global__ __launch_bounds__(256)
void proj_gemm(const float* __restrict__ x, const float* __restrict__ mem,
               const int* __restrict__ active,
               const unsigned short* __restrict__ wB,
               const float* __restrict__ attn_b, const float* __restrict__ pattn_b,
               unsigned short* __restrict__ q1b, unsigned short* __restrict__ k1b,
               unsigned short* __restrict__ v1b, unsigned short* __restrict__ k2b,
               unsigned short* __restrict__ v2b) {
    const int s  = blockIdx.y >> 2;       // 0:Q1 1:K1 2:V1 3:K2 4:V2
    const int n0 = (blockIdx.y & 3) * 64;
    const float* Asrc = (s < 3) ? x : mem;
    const bool useMask = (s < 3);
    const int wtIdx = (s < 3) ? s : (s + 2);            // K2->5, V2->6
    const unsigned short* WT = wB + (size_t)wtIdx * 65536;
    const float* bias = (s < 3) ? (attn_b + s * 256) : (pattn_b + (s - 2) * 256);
    unsigned short* outB;
    switch (s) { case 0: outB = q1b; break; case 1: outB = k1b; break;
                 case 2: outB = v1b; break; case 3: outB = k2b; break;
                 default: outB = v2b; }

    const int tid = threadIdx.x;
    const int wave = tid >> 6, lane = tid & 63;
    const int m0 = blockIdx.x * 64 + wave * 16;
    const int lr = lane & 15;
    const int lk = (lane >> 4) << 3;
    const int arowIdx = m0 + lr;
    const bool rowAct = !useMask || act_at(active, arowIdx >> 6, arowIdx & 63);

    f32x4 acc[4] = {};
    const float* arow = Asrc + (size_t)arowIdx * 256 + lk;
    const unsigned short* brow = WT + (size_t)(n0 + lr) * 256 + lk;
    #pragma unroll
    for (int kk = 0; kk < 256; kk += 32) {
        float4 a0 = *(const float4*)(arow + kk);
        float4 a1 = *(const float4*)(arow + kk + 4);
        short8 a;
        a[0] = rowAct ? (short)f2b(a0.x) : (short)0;
        a[1] = rowAct ? (short)f2b(a0.y) : (short)0;
        a[2] = rowAct ? (short)f2b(a0.z) : (short)0;
        a[3] = rowAct ? (short)f2b(a0.w) : (short)0;
        a[4] = rowAct ? (short)f2b(a1.x) : (short)0;
        a[5] = rowAct ? (short)f2b(a1.y) : (short)0;
        a[6] = rowAct ? (short)f2b(a1.z) : (short)0;
        a[7] = rowAct ? (short)f2b(a1.w) : (short)0;
        #pragma unroll
        for (int nf = 0; nf < 4; ++nf) {
            short8 b = *(const short8*)(brow + (size_t)nf * 16 * 256 + kk);
            acc[nf] = __builtin_amdgcn_mfma_f32_16x16x32_bf16(a, b, acc[nf], 0, 0, 0);
        }
    }
    const int rbase = m0 + ((lane >> 4) << 2);
    #pragma unroll
    for (int nf = 0; nf < 4; ++nf) {
        int c = n0 + nf * 16 + lr;
        float bc = bias[c];
        #pragma unroll
        for (int jj = 0; jj < 4; ++jj)
            outB[(size_t)(rbase + jj) * 256 + c] = f2b(acc[nf][jj] + bc);
    }
}

// ---------------- dynamic LDS layout (150016 B) ----------------
#define BK_OFF   0            // K union: 100 x 256 bf16 = 51200
#define BV_OFF   51200        // V union: 51200
#define WGT_OFF  102400       // [16][8][25] f32 = 12800
#define T1B_OFF  115200       // [16][264] bf16 = 8448
#define SB_OFF   123648       // [16][264] bf16 = 8448
#define HB_OFF   132096       // [16][520] bf16 = 16640
#define ACT_OFF  148736       // 128
#define REDA_OFF 148864       // [16][8] f32 = 512
#define REDB_OFF 149376       // 512
#define STAT_OFF 149888       // 128
#define SMEM_SZ  150016

// union chunk -> (row, part); row layout: u = r*20 + (m + c), 100 rows
__device__ __forceinline__ int union_row(int c, int h, int w0, int fallback) {
    int u = c >> 5;
    int r = u / 20;
    int hh = h - 2 + r, ww = w0 - 2 + (u - r * 20);
    bool ib = ((unsigned)hh < GH) && ((unsigned)ww < GW);
    return ib ? ((hh << 6) | ww) : fallback;
}

__device__ __forceinline__ void load_union_lds(const unsigned short* __restrict__ base,
                                               int h, int w0, int fallback,
                                               unsigned short (*dst)[256], int tid) {
    for (int c = tid; c < 3200; c += 512) {
        int row = union_row(c, h, w0, fallback);
        int u = c >> 5, part = c & 31;
        *(uint4*)&dst[u][part * 8] = *(const uint4*)(base + (size_t)row * 256 + part * 8);
    }
}

// ---------------- fused chain kernel ----------------
__global__ __launch_bounds__(512)
void fused_kernel(const int* __restrict__ active, const float* __restrict__ x,
                  const unsigned short* __restrict__ wB,
                  const float* __restrict__ attn_b, const float* __restrict__ pattn_b,
                  const float* __restrict__ ff_b1, const float* __restrict__ ff_b2,
                  const float* __restrict__ ln_g, const float* __restrict__ ln_b,
                  const unsigned short* __restrict__ q1b,
                  const unsigned short* __restrict__ k1b,
                  const unsigned short* __restrict__ v1b,
                  const unsigned short* __restrict__ k2b,
                  const unsigned short* __restrict__ v2b,
                  float* __restrict__ out) {
    extern __shared__ __align__(16) char smem[];
    unsigned short (*bufK)[256] = (unsigned short(*)[256])(smem + BK_OFF);
    unsigned short (*bufV)[256] = (unsigned short(*)[256])(smem + BV_OFF);
    float (*wgt)[8][25]         = (float(*)[8][25])(smem + WGT_OFF);
    unsigned short (*T1b)[264]  = (unsigned short(*)[264])(smem + T1B_OFF);
    unsigned short (*Sb)[264]   = (unsigned short(*)[264])(smem + SB_OFF);
    unsigned short (*Hb)[520]   = (unsigned short(*)[520])(smem + HB_OFF);
    unsigned char* actU         = (unsigned char*)(smem + ACT_OFF);
    float (*redA)[8]            = (float(*)[8])(smem + REDA_OFF);
    float (*redB)[8]            = (float(*)[8])(smem + REDB_OFF);
    float (*stats)[2]           = (float(*)[2])(smem + STAT_OFF);

    const int tid = threadIdx.x;
    const int wv = tid >> 6, lane = tid & 63;
    const int lr = lane & 15, qi = lane >> 4;
    const int half = lane >> 5, lam = lane & 31;
    const int m = wv * 2 + half;              // node 0..15
    const int bid = ((blockIdx.x & 7) << 5) | (blockIdx.x >> 3);   // XCD-chunked
    const int n0 = bid * 16;
    const int h = n0 >> 6, w0 = n0 & 63;

    // ---- P0: masks + K1 & V1 unions (latencies overlap) ----
    if (tid < 100) {
        int r = tid / 20;
        int hh = h - 2 + r, ww = w0 - 2 + (tid - r * 20);
        actU[tid] = act_at(active, hh, ww) ? 1 : 0;
    }
    load_union_lds(k1b, h, w0, 0, bufK, tid);
    load_union_lds(v1b, h, w0, 0, bufV, tid);
    __syncthreads();

    // ---- P1: attn1 scores ----
    {
        float q[8];
        short8 qv = *(const short8*)(q1b + (size_t)(n0 + m) * 256 + lam * 8);
        #pragma unroll
        for (int j = 0; j < 8; ++j) q[j] = b2f(qv[j]);
        #pragma unroll 5
        for (int l = 0; l < L; ++l) {
            int u = (l / 5) * 20 + m + (l % 5);
            short8 kv = *(const short8*)&bufK[u][lam * 8];
            float p = q[0] * b2f(kv[0]);
            #pragma unroll
            for (int j = 1; j < 8; ++j) p = fmaf(q[j], b2f(kv[j]), p);
            p += __shfl_xor(p, 1); p += __shfl_xor(p, 2);
            float sv = actU[u] ? p * SCALE : -1e30f;
            if ((lam & 3) == 0) wgt[m][lam >> 2][l] = sv;
        }
    }
    __syncthreads();

    // ---- P2: softmax1 (tid<128) + K2 prefetch -> regs -> bufK ----
    uint4 pre[7];
    {
        #pragma unroll
        for (int k = 0; k < 7; ++k) {
            int c = tid + k * 512;
            int cc = (c < 3200) ? c : 3199;
            int row = union_row(cc, h, w0, NN);       // OOB -> bias row
            pre[k] = *(const uint4*)(k2b + (size_t)row * 256 + (cc & 31) * 8);
        }
        if (tid < 128) {
            int mm = tid >> 3, hd = tid & 7;
            float mx = -1e30f;
            for (int l = 0; l < L; ++l) mx = fmaxf(mx, wgt[mm][hd][l]);
            float sum = 0.0f;
            for (int l = 0; l < L; ++l) { float e = expf(wgt[mm][hd][l] - mx); wgt[mm][hd][l] = e; sum += e; }
            float inv = 1.0f / sum;
            for (int l = 0; l < L; ++l) wgt[mm][hd][l] *= inv;
        }
        #pragma unroll
        for (int k = 0; k < 7; ++k) {
            int c = tid + k * 512;
            if (c < 3200)
                *(uint4*)&bufK[c >> 5][(c & 31) * 8] = pre[k];   // bufK dead since P1 barrier
        }
    }
    __syncthreads();

    // ---- P3: PV1 (bufV) -> T1b ; V2 prefetch -> regs ----
    {
        #pragma unroll
        for (int k = 0; k < 7; ++k) {
            int c = tid + k * 512;
            int cc = (c < 3200) ? c : 3199;
            int row = union_row(cc, h, w0, NN);
            pre[k] = *(const uint4*)(v2b + (size_t)row * 256 + (cc & 31) * 8);
        }
        float o[8] = {0.f,0.f,0.f,0.f,0.f,0.f,0.f,0.f};
        #pragma unroll 5
        for (int l = 0; l < L; ++l) {
            int u = (l / 5) * 20 + m + (l % 5);
            if (actU[u]) {
                float wt = wgt[m][lam >> 2][l];
                short8 v8 = *(const short8*)&bufV[u][lam * 8];
                #pragma unroll
                for (int j = 0; j < 8; ++j) o[j] = fmaf(wt, b2f(v8[j]), o[j]);
            }
        }
        unsigned short u8[8];
        #pragma unroll
        for (int j = 0; j < 8; ++j) u8[j] = f2b(o[j]);
        *(uint4*)&T1b[m][lam * 8] = *(uint4*)u8;     // T1b separate region
    }
    __syncthreads();

    // ---- P4: write V2 -> bufV ; Wo1 + bias + resid(x) + LN0 -> sreg + Sb ----
    float sreg[2][4];
    {
        #pragma unroll
        for (int k = 0; k < 7; ++k) {
            int c = tid + k * 512;
            if (c < 3200)
                *(uint4*)&bufV[c >> 5][(c & 31) * 8] = pre[k];   // bufV dead after P3 barrier
        }
        const unsigned short* Wo1T = wB + 3 * 65536;
        f32x4 acc[2] = {};
        #pragma unroll
        for (int kk = 0; kk < 256; kk += 32) {
            short8 a = *(const short8*)&T1b[lr][qi * 8 + kk];
            #pragma unroll
            for (int nf = 0; nf < 2; ++nf) {
                short8 b = *(const short8*)(Wo1T + (size_t)(wv * 32 + nf * 16 + lr) * 256 + qi * 8 + kk);
                acc[nf] = __builtin_amdgcn_mfma_f32_16x16x32_bf16(a, b, acc[nf], 0, 0, 0);
            }
        }
        float v[2][4], s1[4] = {0.f,0.f,0.f,0.f}, s2[4] = {0.f,0.f,0.f,0.f};
        #pragma unroll
        for (int nf = 0; nf < 2; ++nf) {
            int c = wv * 32 + nf * 16 + lr;
            float bc = attn_b[768 + c];
            #pragma unroll
            for (int jj = 0; jj < 4; ++jj) {
                int row = n0 + qi * 4 + jj;
                float vv = acc[nf][jj] + bc + x[(size_t)row * D + c];
                v[nf][jj] = vv; s1[jj] += vv; s2[jj] += vv * vv;
            }
        }
        #pragma unroll
        for (int jj = 0; jj < 4; ++jj) {
            #pragma unroll
            for (int off = 1; off < 16; off <<= 1) {
                s1[jj] += __shfl_xor(s1[jj], off);
                s2[jj] += __shfl_xor(s2[jj], off);
            }
        }
        if (lr == 0) {
            #pragma unroll
            for (int jj = 0; jj < 4; ++jj) { redA[qi*4+jj][wv] = s1[jj]; redB[qi*4+jj][wv] = s2[jj]; }
        }
        __syncthreads();
        if (tid < 16) {
            float a1 = 0.f, a2 = 0.f;
            #pragma unroll
            for (int q8 = 0; q8 < 8; ++q8) { a1 += redA[tid][q8]; a2 += redB[tid][q8]; }
            float mu = a1 * (1.0f / D);
            float var = a2 * (1.0f / D) - mu * mu;
            stats[tid][0] = mu; stats[tid][1] = rsqrtf(var + EPS);
        }
        __syncthreads();
        #pragma unroll
        for (int nf = 0; nf < 2; ++nf) {
            int c = wv * 32 + nf * 16 + lr;
            float gg = ln_g[c], bb = ln_b[c];
            #pragma unroll
            for (int jj = 0; jj < 4; ++jj) {
                int ridx = qi * 4 + jj;
                float ov = (v[nf][jj] - stats[ridx][0]) * stats[ridx][1] * gg + bb;
                sreg[nf][jj] = ov;
                Sb[ridx][c] = f2b(ov);
            }
        }
    }
    __syncthreads();

    // ---- P5: Wq2 (Sb) -> T1b stage -> q2 regs ----
    float q2[8];
    {
        const unsigned short* Wq2T = wB + 4 * 65536;
        f32x4 acc[2] = {};
        #pragma unroll
        for (int kk = 0; kk < 256; kk += 32) {
            short8 a = *(const short8*)&Sb[lr][qi * 8 + kk];
            #pragma unroll
            for (int nf = 0; nf < 2; ++nf) {
                short8 b = *(const short8*)(Wq2T + (size_t)(wv * 32 + nf * 16 + lr) * 256 + qi * 8 + kk);
                acc[nf] = __builtin_amdgcn_mfma_f32_16x16x32_bf16(a, b, acc[nf], 0, 0, 0);
            }
        }
        __syncthreads();   // T1b (old T1) fully consumed in P4
        #pragma unroll
        for (int nf = 0; nf < 2; ++nf) {
            int c = wv * 32 + nf * 16 + lr;
            float bc = pattn_b[c];
            #pragma unroll
            for (int jj = 0; jj < 4; ++jj)
                T1b[qi * 4 + jj][c] = f2b(acc[nf][jj] + bc);
        }
        __syncthreads();
        short8 qv = *(const short8*)&T1b[m][lam * 8];
        #pragma unroll
        for (int j = 0; j < 8; ++j) q2[j] = b2f(qv[j]);
    }
    // no barrier needed: next T1b write (P7) is separated by P6 barriers

    // ---- P6: attn2 scores (bufK = K2, already resident) ----
    #pragma unroll 5
    for (int l = 0; l < L; ++l) {
        int u = (l / 5) * 20 + m + (l % 5);
        short8 kv = *(const short8*)&bufK[u][lam * 8];
        float p = q2[0] * b2f(kv[0]);
        #pragma unroll
        for (int j = 1; j < 8; ++j) p = fmaf(q2[j], b2f(kv[j]), p);
        p += __shfl_xor(p, 1); p += __shfl_xor(p, 2);
        if ((lam & 3) == 0) wgt[m][lam >> 2][l] = p * SCALE;
    }
    __syncthreads();
    if (tid < 128) {
        int mm = tid >> 3, hd = tid & 7;
        float mx = -1e30f;
        for (int l = 0; l < L; ++l) mx = fmaxf(mx, wgt[mm][hd][l]);
        float sum = 0.0f;
        for (int l = 0; l < L; ++l) { float e = expf(wgt[mm][hd][l] - mx); wgt[mm][hd][l] = e; sum += e; }
        float inv = 1.0f / sum;
        for (int l = 0; l < L; ++l) wgt[mm][hd][l] *= inv;
    }
    __syncthreads();

    // ---- P7: PV2 (bufV = V2, resident) -> T1b ----
    {
        float o[8] = {0.f,0.f,0.f,0.f,0.f,0.f,0.f,0.f};
        #pragma unroll 5
        for (int l = 0; l < L; ++l) {
            int u = (l / 5) * 20 + m + (l % 5);
            float wt = wgt[m][lam >> 2][l];
            short8 v8 = *(const short8*)&bufV[u][lam * 8];
            #pragma unroll
            for (int j = 0; j < 8; ++j) o[j] = fmaf(wt, b2f(v8[j]), o[j]);
        }
        unsigned short u8[8];
        #pragma unroll
        for (int j = 0; j < 8; ++j) u8[j] = f2b(o[j]);
        *(uint4*)&T1b[m][lam * 8] = *(uint4*)u8;
    }
    __syncthreads();

    // ---- P8: Wo2 + bias + resid(sreg) + LN2 -> s2reg + Sb ----
    float s2reg[2][4];
    {
        const unsigned short* Wo2T = wB + 7 * 65536;
        f32x4 acc[2] = {};
        #pragma unroll
        for (int kk = 0; kk < 256; kk += 32) {
            short8 a = *(const short8*)&T1b[lr][qi * 8 + kk];
            #pragma unroll
            for (int nf = 0; nf < 2; ++nf) {
                short8 b = *(const short8*)(Wo2T + (size_t)(wv * 32 + nf * 16 + lr) * 256 + qi * 8 + kk);
                acc[nf] = __builtin_amdgcn_mfma_f32_16x16x32_bf16(a, b, acc[nf], 0, 0, 0);
            }
        }
        float v[2][4], s1[4] = {0.f,0.f,0.f,0.f}, s2[4] = {0.f,0.f,0.f,0.f};
        #pragma unroll
        for (int nf = 0; nf < 2; ++nf) {
            int c = wv * 32 + nf * 16 + lr;
            float bc = pattn_b[768 + c];
            #pragma unroll
            for (int jj = 0; jj < 4; ++jj) {
                float vv = acc[nf][jj] + bc + sreg[nf][jj];
                v[nf][jj] = vv; s1[jj] += vv; s2[jj] += vv * vv;
            }
        }
        #pragma unroll
        for (int jj = 0; jj < 4; ++jj) {
            #pragma unroll
            for (int off = 1; off < 16; off <<= 1) {
                s1[jj] += __shfl_xor(s1[jj], off);
                s2[jj] += __shfl_xor(s2[jj], off);
            }
        }
        if (lr == 0) {
            #pragma unroll
            for (int jj = 0; jj < 4; ++jj) { redA[qi*4+jj][wv] = s1[jj]; redB[qi*4+jj][wv] = s2[jj]; }
        }
        __syncthreads();
        if (tid < 16) {
            float a1 = 0.f, a2 = 0.f;
            #pragma unroll
            for (int q8 = 0; q8 < 8; ++q8) { a1 += redA[tid][q8]; a2 += redB[tid][q8]; }
            float mu = a1 * (1.0f / D);
            float var = a2 * (1.0f / D) - mu * mu;
            stats[tid][0] = mu; stats[tid][1] = rsqrtf(var + EPS);
        }
        __syncthreads();
        #pragma unroll
        for (int nf = 0; nf < 2; ++nf) {
            int c = wv * 32 + nf * 16 + lr;
            float gg = ln_g[512 + c], bb = ln_b[512 + c];
            #pragma unroll
            for (int jj = 0; jj < 4; ++jj) {
                int ridx = qi * 4 + jj;
                float ov = (v[nf][jj] - stats[ridx][0]) * stats[ridx][1] * gg + bb;
                s2reg[nf][jj] = ov;
                Sb[ridx][c] = f2b(ov);
            }
        }
    }
    __syncthreads();

    // ---- P9: FF1 (Sb) -> Hb ----
    {
        const unsigned short* W1T = wB + 524288;
        f32x4 acc[4] = {};
        #pragma unroll
        for (int kk = 0; kk < 256; kk += 32) {
            short8 a = *(const short8*)&Sb[lr][qi * 8 + kk];
            #pragma unroll
            for (int nf = 0; nf < 4; ++nf) {
                short8 b = *(const short8*)(W1T + (size_t)(wv * 64 + nf * 16 + lr) * 256 + qi * 8 + kk);
                acc[nf] = __builtin_amdgcn_mfma_f32_16x16x32_bf16(a, b, acc[nf], 0, 0, 0);
            }
        }
        #pragma unroll
        for (int nf = 0; nf < 4; ++nf) {
            int c = wv * 64 + nf * 16 + lr;
            float bc = ff_b1[c];
            #pragma unroll
            for (int jj = 0; jj < 4; ++jj)
                Hb[qi * 4 + jj][c] = f2b(fmaxf(acc[nf][jj] + bc, 0.0f));
        }
    }
    __syncthreads();

    // ---- P10: FF2 (K=512) + resid(s2reg) + LN1 + mask -> out ----
    {
        const unsigned short* W2T = wB + 655360;
        f32x4 acc[2] = {};
        #pragma unroll
        for (int kk = 0; kk < 512; kk += 32) {
            short8 a = *(const short8*)&Hb[lr][qi * 8 + kk];
            #pragma unroll
            for (int nf = 0; nf < 2; ++nf) {
                short8 b = *(const short8*)(W2T + (size_t)(wv * 32 + nf * 16 + lr) * 512 + qi * 8 + kk);
                acc[nf] = __builtin_amdgcn_mfma_f32_16x16x32_bf16(a, b, acc[nf], 0, 0, 0);
            }
        }
        float v[2][4], s1[4] = {0.f,0.f,0.f,0.f}, s2[4] = {0.f,0.f,0.f,0.f};
        #pragma unroll
        for (int nf = 0; nf < 2; ++nf) {
            int c = wv * 32 + nf * 16 + lr;
            float bc = ff_b2[c];
            #pragma unroll
            for (int jj = 0; jj < 4; ++jj) {
                float vv = acc[nf][jj] + bc + s2reg[nf][jj];
                v[nf][jj] = vv; s1[jj] += vv; s2[jj] += vv * vv;
            }
        }
        #pragma unroll
        for (int jj = 0; jj < 4; ++jj) {
            #pragma unroll
            for (int off = 1; off < 16; off <<= 1) {
                s1[jj] += __shfl_xor(s1[jj], off);
                s2[jj] += __shfl_xor(s2[jj], off);
            }
        }
        if (lr == 0) {
            #pragma unroll
            for (int jj = 0; jj < 4; ++jj) { redA[qi*4+jj][wv] = s1[jj]; redB[qi*4+jj][wv] = s2[jj]; }
        }
        __syncthreads();
        if (tid < 16) {
            float a1 = 0.f, a2 = 0.f;
            #pragma unroll
            for (int q8 = 0; q8 < 8; ++q8) { a1 += redA[tid][q8]; a2 += redB[tid][q8]; }
            float mu = a1 * (1.0f / D);
            float var = a2 * (1.0f / D) - mu * mu;
            stats[tid][0] = mu; stats[tid][1] = rsqrtf(var + EPS);
        }
        __syncthreads();
        bool arow_act[4];
        #pragma unroll
        for (int jj = 0; jj < 4; ++jj) {
            int row = n0 + qi * 4 + jj;
            arow_act[jj] = act_at(active, row >> 6, row & 63);
        }
        #pragma unroll
        for (int nf = 0; nf < 2; ++nf) {
            int c = wv * 32 + nf * 16 + lr;
            float gg = ln_g[256 + c], bb = ln_b[256 + c];
            #pragma unroll
            for (int jj = 0; jj < 4; ++jj) {
                int ridx = qi * 4 + jj;
                float ov = (v[nf][jj] - stats[ridx][0]) * stats[ridx][1] * gg + bb;
                out[(size_t)(n0 + ridx) * D + c] = arow_act[jj] ? ov : 0.0f;
            }
        }
        if (tid < 16) {
            int row = n0 + tid;
            out[(size_t)NND + row] = act_at(active, row >> 6, row & 63) ? 1.0f : 0.0f;
        }
    }
}

extern "C" void kernel_launch(void* const* d_in, const int* in_sizes, int n_in,
                              void* d_out, int out_size, void* d_ws, size_t ws_size,
                              hipStream_t stream) {
    const float* x       = (const float*)d_in[0];
    const float* memory  = (const float*)d_in[1];
    const int*   active  = (const int*)d_in[2];
    const float* attn_w  = (const float*)d_in[3];
    const float* attn_b  = (const float*)d_in[4];
    const float* pattn_w = (const float*)d_in[5];
    const float* pattn_b = (const float*)d_in[6];
    const float* ff_w1   = (const float*)d_in[7];
    const float* ff_b1   = (const float*)d_in[8];
    const float* ff_w2   = (const float*)d_in[9];
    const float* ff_b2   = (const float*)d_in[10];
    const float* ln_g    = (const float*)d_in[11];
    const float* ln_b    = (const float*)d_in[12];
    float* out = (float*)d_out;

    unsigned short* wsb = (unsigned short*)d_ws;
    unsigned short* wB   = wsb;                                 // 786432 shorts
    unsigned short* q1b  = wB + 786432;
    unsigned short* k1b  = q1b + (size_t)NND;
    unsigned short* v1b  = k1b + (size_t)NND;
    unsigned short* k2b  = v1b + (size_t)NND;                   // 4097 rows
    unsigned short* v2b  = k2b + (size_t)NND + 256;             // 4097 rows

    static int attr_set = 0;
    if (!attr_set) {
        hipFuncSetAttribute(reinterpret_cast<const void*>(fused_kernel),
                            hipFuncAttributeMaxDynamicSharedMemorySize, SMEM_SZ);
        attr_set = 1;
    }

    hipLaunchKernelGGL(prep_kernel, dim3(193), dim3(256), 0, stream,
                       attn_w, pattn_w, ff_w1, ff_w2, pattn_b,
                       wB, k2b + (size_t)NND, v2b + (size_t)NND);
    hipLaunchKernelGGL(proj_gemm, dim3(64, 20), dim3(256), 0, stream,
                       x, memory, active, wB, attn_b, pattn_b,
                       q1b, k1b, v1b, k2b, v2b);
    hipLaunchKernelGGL(fused_kernel, dim3(256), dim3(512), SMEM_SZ, stream,
                       active, x, wB, attn_b, pattn_b, ff_b1, ff_b2, ln_g, ln_b,
                       q1b, k1b, v1b, k2b, v2b, out);
}

// Round 12
// 89.629 us; speedup vs baseline: 1.4396x; 1.1399x over previous
//
#include <hip/hip_runtime.h>
#include <math.h>

#define D 256
#define H2 512
#define HEADS 8
#define L 25
#define GH 64
#define GW 64
#define NN 4096
#define EPS 1e-5f
#define SCALE 0.17677669529663687f  // 1/sqrt(32)
#define NND 1048576                 // NN*D

typedef __attribute__((ext_vector_type(8))) short short8;
typedef __attribute__((ext_vector_type(4))) float f32x4;

__device__ __forceinline__ bool act_at(const int* __restrict__ active, int h, int w) {
    if (h < 0 || h >= GH || w < 0 || w >= GW) return false;
    if (h == 2 && w == 2) return false;   // ap.at[:, center, center].set(False) quirk
    return active[h * GW + w] != 0;
}

__device__ __forceinline__ unsigned short f2b(float f) {
    unsigned u = __float_as_uint(f);
    u += 0x7fffu + ((u >> 16) & 1u);      // RNE
    return (unsigned short)(u >> 16);
}
__device__ __forceinline__ float b2f(short v) {
    return __uint_as_float(((unsigned)(unsigned short)v) << 16);
}

// async global->LDS DMA, 16 B per lane; lds dest = wave-uniform base + lane*16
__device__ __forceinline__ void dma16(const unsigned short* g, unsigned short* l) {
    __builtin_amdgcn_global_load_lds(
        (const __attribute__((address_space(1))) unsigned int*)g,
        (__attribute__((address_space(3))) unsigned int*)l, 16, 0, 0);
}

// ---------------- prep: bf16 conversions + LDS-tiled weight transposes (R9) --------
__global__ __launch_bounds__(256)
void prep_kernel(const float* __restrict__ x, const float* __restrict__ mem,
                 const int* __restrict__ active,
                 const float* __restrict__ attn_w, const float* __restrict__ pattn_w,
                 const float* __restrict__ ff_w1, const float* __restrict__ ff_w2,
                 const float* __restrict__ pattn_b,
                 unsigned short* __restrict__ xmB, unsigned short* __restrict__ memB,
                 unsigned short* __restrict__ wB,
                 unsigned short* __restrict__ k2bias, unsigned short* __restrict__ v2bias) {
    const int tid = threadIdx.x;
    const int bid = blockIdx.x;
    if (bid < 192) {
        __shared__ float tile[64][65];
        const float* src; unsigned short* dst;
        int i0, n0, srcLen, dstLen;
        if (bid < 128) {
            int mat = bid >> 4, t16 = bid & 15;
            i0 = (t16 >> 2) * 64; n0 = (t16 & 3) * 64;
            src = (mat < 4) ? (attn_w + mat * 65536) : (pattn_w + (mat - 4) * 65536);
            dst = wB + mat * 65536;
            srcLen = 256; dstLen = 256;
        } else if (bid < 160) {
            int t = bid - 128;
            i0 = (t >> 3) * 64; n0 = (t & 7) * 64;
            src = ff_w1; dst = wB + 524288;      // W1T: [512][256]
            srcLen = 512; dstLen = 256;
        } else {
            int t = bid - 160;
            i0 = (t >> 2) * 64; n0 = (t & 3) * 64;
            src = ff_w2; dst = wB + 655360;      // W2T: [256][512]
            srcLen = 256; dstLen = 512;
        }
        int c = tid & 63, r4 = tid >> 6;
        for (int rr = 0; rr < 64; rr += 4)
            tile[rr + r4][c] = src[(size_t)(i0 + rr + r4) * srcLen + n0 + c];
        __syncthreads();
        for (int rr = 0; rr < 64; rr += 4) {
            int r = rr + r4;
            dst[(size_t)(n0 + r) * dstLen + i0 + c] = f2b(tile[c][r]);
        }
    } else {
        const int t0 = (bid - 192) * 256 + tid;
        for (int t = t0; t < 524800; t += 512 * 256) {
            if (t < 262144) {
                int n = t >> 6;
                bool a = act_at(active, n >> 6, n & 63);
                float4 v = ((const float4*)x)[t];
                ushort4 u;
                u.x = f2b(a ? v.x : 0.0f); u.y = f2b(a ? v.y : 0.0f);
                u.z = f2b(a ? v.z : 0.0f); u.w = f2b(a ? v.w : 0.0f);
                ((ushort4*)xmB)[t] = u;
            } else if (t < 524288) {
                int tt = t - 262144;
                float4 v = ((const float4*)mem)[tt];
                ushort4 u;
                u.x = f2b(v.x); u.y = f2b(v.y); u.z = f2b(v.z); u.w = f2b(v.w);
                ((ushort4*)memB)[tt] = u;
            } else {
                int tt = t - 524288;   // 512 scalars: K2/V2 bias rows (row 4096, bf16)
                if (tt < 256) k2bias[tt] = f2b(pattn_b[256 + tt]);
                else          v2bias[tt - 256] = f2b(pattn_b[512 + (tt - 256)]);
            }
        }
    }
}

// ---------------- proj: 5 GEMM streams -> bf16 outputs (R9) ----------------
__global__ __launch_bounds__(256)
void proj_gemm(const unsigned short* __restrict__ xmB,
               const unsigned short* __restrict__ memB,
               const unsigned short* __restrict__ wB,
               const float* __restrict__ attn_b, const float* __restrict__ pattn_b,
               unsigned short* __restrict__ q1b, unsigned short* __restrict__ k1b,
               unsigned short* __restrict__ v1b, unsigned short* __restrict__ k2b,
               unsigned short* __restrict__ v2b) {
    const int s  = blockIdx.y >> 2;       // 0:Q1 1:K1 2:V1 3:K2 4:V2
    const int n0 = (blockIdx.y & 3) * 64;
    const unsigned short* A  = (s < 3) ? xmB : memB;
    const int wtIdx = (s < 3) ? s : (s + 2);            // K2->5, V2->6
    const unsigned short* WT = wB + (size_t)wtIdx * 65536;
    const float* bias = (s < 3) ? (attn_b + s * 256) : (pattn_b + (s - 2) * 256);
    unsigned short* outB;
    switch (s) { case 0: outB = q1b; break; case 1: outB = k1b; break;
                 case 2: outB = v1b; break; case 3: outB = k2b; break;
                 default: outB = v2b; }

    const int tid = threadIdx.x;
    const int wave = tid >> 6, lane = tid & 63;
    const int m0 = blockIdx.x * 64 + wave * 16;
    const int lr = lane & 15;
    const int lk = (lane >> 4) << 3;
    f32x4 acc[4] = {};
    const unsigned short* arow = A  + (size_t)(m0 + lr) * 256 + lk;
    const unsigned short* brow = WT + (size_t)(n0 + lr) * 256 + lk;
    #pragma unroll
    for (int kk = 0; kk < 256; kk += 32) {
        short8 a = *(const short8*)(arow + kk);
        #pragma unroll
        for (int nf = 0; nf < 4; ++nf) {
            short8 b = *(const short8*)(brow + (size_t)nf * 16 * 256 + kk);
            acc[nf] = __builtin_amdgcn_mfma_f32_16x16x32_bf16(a, b, acc[nf], 0, 0, 0);
        }
    }
    const int rbase = m0 + ((lane >> 4) << 2);
    #pragma unroll
    for (int nf = 0; nf < 4; ++nf) {
        int c = n0 + nf * 16 + lr;
        float bc = bias[c];
        #pragma unroll
        for (int jj = 0; jj < 4; ++jj)
            outB[(size_t)(rbase + jj) * 256 + c] = f2b(acc[nf][jj] + bc);
    }
}

// ---------------- dynamic LDS layout (150016 B, all regions separate) ----------------
#define BK_OFF   0            // K union: 100 x 256 bf16 = 51200
#define BV_OFF   51200        // V union: 51200
#define WGT_OFF  102400       // [16][8][25] f32 = 12800
#define T1B_OFF  115200       // [16][264] bf16 = 8448
#define SB_OFF   123648       // [16][264] bf16 = 8448
#define HB_OFF   132096       // [16][520] bf16 = 16640
#define ACT_OFF  148736       // 128
#define REDA_OFF 148864       // [16][8] f32 = 512
#define REDB_OFF 149376       // 512
#define STAT_OFF 149888       // 128
#define SMEM_SZ  150016

__device__ __forceinline__ int union_row(int c, int h, int w0, int fallback) {
    int u = c >> 5;
    int r = u / 20;
    int hh = h - 2 + r, ww = w0 - 2 + (u - r * 20);
    bool ib = ((unsigned)hh < GH) && ((unsigned)ww < GW);
    return ib ? ((hh << 6) | ww) : fallback;
}

// 3200 chunks = 6.25 x 512 threads; tail (k=6) is exactly 2 full waves -> no partial wave
__device__ __forceinline__ void dma_union(const unsigned short* __restrict__ base,
                                          int h, int w0, int fallback,
                                          unsigned short* dstLds, int tid) {
    #pragma unroll
    for (int k = 0; k < 7; ++k) {
        int c = tid + k * 512;
        if (c < 3200) {
            int row = union_row(c, h, w0, fallback);
            dma16(base + (size_t)row * 256 + (c & 31) * 8, dstLds + (size_t)c * 8);
        }
    }
}

// ---------------- fused chain kernel ----------------
__global__ __launch_bounds__(512)
void fused_kernel(const int* __restrict__ active, const float* __restrict__ x,
                  const unsigned short* __restrict__ wB,
                  const float* __restrict__ attn_b, const float* __restrict__ pattn_b,
                  const float* __restrict__ ff_b1, const float* __restrict__ ff_b2,
                  const float* __restrict__ ln_g, const float* __restrict__ ln_b,
                  const unsigned short* __restrict__ q1b,
                  const unsigned short* __restrict__ k1b,
                  const unsigned short* __restrict__ v1b,
                  const unsigned short* __restrict__ k2b,
                  const unsigned short* __restrict__ v2b,
                  float* __restrict__ out) {
    extern __shared__ __align__(16) char smem[];
    unsigned short (*bufK)[256] = (unsigned short(*)[256])(smem + BK_OFF);
    unsigned short (*bufV)[256] = (unsigned short(*)[256])(smem + BV_OFF);
    float (*wgt)[8][25]         = (float(*)[8][25])(smem + WGT_OFF);
    unsigned short (*T1b)[264]  = (unsigned short(*)[264])(smem + T1B_OFF);
    unsigned short (*Sb)[264]   = (unsigned short(*)[264])(smem + SB_OFF);
    unsigned short (*Hb)[520]   = (unsigned short(*)[520])(smem + HB_OFF);
    unsigned char* actU         = (unsigned char*)(smem + ACT_OFF);
    float (*redA)[8]            = (float(*)[8])(smem + REDA_OFF);
    float (*redB)[8]            = (float(*)[8])(smem + REDB_OFF);
    float (*stats)[2]           = (float(*)[2])(smem + STAT_OFF);

    const int tid = threadIdx.x;
    const int wv = tid >> 6, lane = tid & 63;
    const int lr = lane & 15, qi = lane >> 4;
    const int half = lane >> 5, lam = lane & 31;
    const int m = wv * 2 + half;              // node 0..15
    const int bid = ((blockIdx.x & 7) << 5) | (blockIdx.x >> 3);   // XCD-chunked
    const int n0 = bid * 16;
    const int h = n0 >> 6, w0 = n0 & 63;

    // ---- P0: masks + K1/V1 unions via async DMA ----
    dma_union(k1b, h, w0, 0, (unsigned short*)(smem + BK_OFF), tid);
    dma_union(v1b, h, w0, 0, (unsigned short*)(smem + BV_OFF), tid);
    if (tid < 100) {
        int r = tid / 20;
        int hh = h - 2 + r, ww = w0 - 2 + (tid - r * 20);
        actU[tid] = act_at(active, hh, ww) ? 1 : 0;
    }
    __syncthreads();

    // ---- P1: attn1 scores (bufK = K1) ----
    {
        float q[8];
        short8 qv = *(const short8*)(q1b + (size_t)(n0 + m) * 256 + lam * 8);
        #pragma unroll
        for (int j = 0; j < 8; ++j) q[j] = b2f(qv[j]);
        #pragma unroll 5
        for (int l = 0; l < L; ++l) {
            int u = (l / 5) * 20 + m + (l % 5);
            short8 kv = *(const short8*)&bufK[u][lam * 8];
            float p = q[0] * b2f(kv[0]);
            #pragma unroll
            for (int j = 1; j < 8; ++j) p = fmaf(q[j], b2f(kv[j]), p);
            p += __shfl_xor(p, 1); p += __shfl_xor(p, 2);
            float sv = actU[u] ? p * SCALE : -1e30f;
            if ((lam & 3) == 0) wgt[m][lam >> 2][l] = sv;
        }
    }
    __syncthreads();

    // ---- P2: issue K2 DMA into bufK (dead), then softmax1 ----
    dma_union(k2b, h, w0, NN, (unsigned short*)(smem + BK_OFF), tid);
    if (tid < 128) {
        int mm = tid >> 3, hd = tid & 7;
        float mx = -1e30f;
        for (int l = 0; l < L; ++l) mx = fmaxf(mx, wgt[mm][hd][l]);
        float sum = 0.0f;
        for (int l = 0; l < L; ++l) { float e = expf(wgt[mm][hd][l] - mx); wgt[mm][hd][l] = e; sum += e; }
        float inv = 1.0f / sum;
        for (int l = 0; l < L; ++l) wgt[mm][hd][l] *= inv;
    }
    __syncthreads();

    // ---- P3: PV1 (bufV = V1) -> T1b ----
    {
        float o[8] = {0.f,0.f,0.f,0.f,0.f,0.f,0.f,0.f};
        #pragma unroll 5
        for (int l = 0; l < L; ++l) {
            int u = (l / 5) * 20 + m + (l % 5);
            if (actU[u]) {
                float wt = wgt[m][lam >> 2][l];
                short8 v8 = *(const short8*)&bufV[u][lam * 8];
                #pragma unroll
                for (int j = 0; j < 8; ++j) o[j] = fmaf(wt, b2f(v8[j]), o[j]);
            }
        }
        unsigned short u8[8];
        #pragma unroll
        for (int j = 0; j < 8; ++j) u8[j] = f2b(o[j]);
        *(uint4*)&T1b[m][lam * 8] = *(uint4*)u8;
    }
    __syncthreads();

    // ---- P4: issue V2 DMA into bufV (dead); Wo1 + bias + resid(x) + LN0 ----
    float sreg[2][4];
    {
        dma_union(v2b, h, w0, NN, (unsigned short*)(smem + BV_OFF), tid);
        const unsigned short* Wo1T = wB + 3 * 65536;
        f32x4 acc[2] = {};
        #pragma unroll
        for (int kk = 0; kk < 256; kk += 32) {
            short8 a = *(const short8*)&T1b[lr][qi * 8 + kk];
            #pragma unroll
            for (int nf = 0; nf < 2; ++nf) {
                short8 b = *(const short8*)(Wo1T + (size_t)(wv * 32 + nf * 16 + lr) * 256 + qi * 8 + kk);
                acc[nf] = __builtin_amdgcn_mfma_f32_16x16x32_bf16(a, b, acc[nf], 0, 0, 0);
            }
        }
        float v[2][4], s1[4] = {0.f,0.f,0.f,0.f}, s2[4] = {0.f,0.f,0.f,0.f};
        #pragma unroll
        for (int nf = 0; nf < 2; ++nf) {
            int c = wv * 32 + nf * 16 + lr;
            float bc = attn_b[768 + c];
            #pragma unroll
            for (int jj = 0; jj < 4; ++jj) {
                int row = n0 + qi * 4 + jj;
                float vv = acc[nf][jj] + bc + x[(size_t)row * D + c];
                v[nf][jj] = vv; s1[jj] += vv; s2[jj] += vv * vv;
            }
        }
        #pragma unroll
        for (int jj = 0; jj < 4; ++jj) {
            #pragma unroll
            for (int off = 1; off < 16; off <<= 1) {
                s1[jj] += __shfl_xor(s1[jj], off);
                s2[jj] += __shfl_xor(s2[jj], off);
            }
        }
        if (lr == 0) {
            #pragma unroll
            for (int jj = 0; jj < 4; ++jj) { redA[qi*4+jj][wv] = s1[jj]; redB[qi*4+jj][wv] = s2[jj]; }
        }
        __syncthreads();
        if (tid < 16) {
            float a1 = 0.f, a2 = 0.f;
            #pragma unroll
            for (int q8 = 0; q8 < 8; ++q8) { a1 += redA[tid][q8]; a2 += redB[tid][q8]; }
            float mu = a1 * (1.0f / D);
            float var = a2 * (1.0f / D) - mu * mu;
            stats[tid][0] = mu; stats[tid][1] = rsqrtf(var + EPS);
        }
        __syncthreads();
        #pragma unroll
        for (int nf = 0; nf < 2; ++nf) {
            int c = wv * 32 + nf * 16 + lr;
            float gg = ln_g[c], bb = ln_b[c];
            #pragma unroll
            for (int jj = 0; jj < 4; ++jj) {
                int ridx = qi * 4 + jj;
                float ov = (v[nf][jj] - stats[ridx][0]) * stats[ridx][1] * gg + bb;
                sreg[nf][jj] = ov;
                Sb[ridx][c] = f2b(ov);
            }
        }
    }
    __syncthreads();

    // ---- P5: Wq2 (Sb) -> T1b -> q2 regs ----
    float q2[8];
    {
        const unsigned short* Wq2T = wB + 4 * 65536;
        f32x4 acc[2] = {};
        #pragma unroll
        for (int kk = 0; kk < 256; kk += 32) {
            short8 a = *(const short8*)&Sb[lr][qi * 8 + kk];
            #pragma unroll
            for (int nf = 0; nf < 2; ++nf) {
                short8 b = *(const short8*)(Wq2T + (size_t)(wv * 32 + nf * 16 + lr) * 256 + qi * 8 + kk);
                acc[nf] = __builtin_amdgcn_mfma_f32_16x16x32_bf16(a, b, acc[nf], 0, 0, 0);
            }
        }
        #pragma unroll
        for (int nf = 0; nf < 2; ++nf) {
            int c = wv * 32 + nf * 16 + lr;
            float bc = pattn_b[c];
            #pragma unroll
            for (int jj = 0; jj < 4; ++jj)
                T1b[qi * 4 + jj][c] = f2b(acc[nf][jj] + bc);
        }
        __syncthreads();
        short8 qv = *(const short8*)&T1b[m][lam * 8];
        #pragma unroll
        for (int j = 0; j < 8; ++j) q2[j] = b2f(qv[j]);
    }

    // ---- P6: attn2 scores (bufK = K2) ----
    #pragma unroll 5
    for (int l = 0; l < L; ++l) {
        int u = (l / 5) * 20 + m + (l % 5);
        short8 kv = *(const short8*)&bufK[u][lam * 8];
        float p = q2[0] * b2f(kv[0]);
        #pragma unroll
        for (int j = 1; j < 8; ++j) p = fmaf(q2[j], b2f(kv[j]), p);
        p += __shfl_xor(p, 1); p += __shfl_xor(p, 2);
        if ((lam & 3) == 0) wgt[m][lam >> 2][l] = p * SCALE;
    }
    __syncthreads();
    if (tid < 128) {
        int mm = tid >> 3, hd = tid & 7;
        float mx = -1e30f;
        for (int l = 0; l < L; ++l) mx = fmaxf(mx, wgt[mm][hd][l]);
        float sum = 0.0f;
        for (int l = 0; l < L; ++l) { float e = expf(wgt[mm][hd][l] - mx); wgt[mm][hd][l] = e; sum += e; }
        float inv = 1.0f / sum;
        for (int l = 0; l < L; ++l) wgt[mm][hd][l] *= inv;
    }
    __syncthreads();

    // ---- P7: PV2 (bufV = V2) -> T1b ----
    {
        float o[8] = {0.f,0.f,0.f,0.f,0.f,0.f,0.f,0.f};
        #pragma unroll 5
        for (int l = 0; l < L; ++l) {
            int u = (l / 5) * 20 + m + (l % 5);
            float wt = wgt[m][lam >> 2][l];
            short8 v8 = *(const short8*)&bufV[u][lam * 8];
            #pragma unroll
            for (int j = 0; j < 8; ++j) o[j] = fmaf(wt, b2f(v8[j]), o[j]);
        }
        unsigned short u8[8];
        #pragma unroll
        for (int j = 0; j < 8; ++j) u8[j] = f2b(o[j]);
        *(uint4*)&T1b[m][lam * 8] = *(uint4*)u8;
    }
    __syncthreads();

    // ---- P8: Wo2 + bias + resid(sreg) + LN2 -> s2reg + Sb ----
    float s2reg[2][4];
    {
        const unsigned short* Wo2T = wB + 7 * 65536;
        f32x4 acc[2] = {};
        #pragma unroll
        for (int kk = 0; kk < 256; kk += 32) {
            short8 a = *(const short8*)&T1b[lr][qi * 8 + kk];
            #pragma unroll
            for (int nf = 0; nf < 2; ++nf) {
                short8 b = *(const short8*)(Wo2T + (size_t)(wv * 32 + nf * 16 + lr) * 256 + qi * 8 + kk);
                acc[nf] = __builtin_amdgcn_mfma_f32_16x16x32_bf16(a, b, acc[nf], 0, 0, 0);
            }
        }
        float v[2][4], s1[4] = {0.f,0.f,0.f,0.f}, s2[4] = {0.f,0.f,0.f,0.f};
        #pragma unroll
        for (int nf = 0; nf < 2; ++nf) {
            int c = wv * 32 + nf * 16 + lr;
            float bc = pattn_b[768 + c];
            #pragma unroll
            for (int jj = 0; jj < 4; ++jj) {
                float vv = acc[nf][jj] + bc + sreg[nf][jj];
                v[nf][jj] = vv; s1[jj] += vv; s2[jj] += vv * vv;
            }
        }
        #pragma unroll
        for (int jj = 0; jj < 4; ++jj) {
            #pragma unroll
            for (int off = 1; off < 16; off <<= 1) {
                s1[jj] += __shfl_xor(s1[jj], off);
                s2[jj] += __shfl_xor(s2[jj], off);
            }
        }
        if (lr == 0) {
            #pragma unroll
            for (int jj = 0; jj < 4; ++jj) { redA[qi*4+jj][wv] = s1[jj]; redB[qi*4+jj][wv] = s2[jj]; }
        }
        __syncthreads();
        if (tid < 16) {
            float a1 = 0.f, a2 = 0.f;
            #pragma unroll
            for (int q8 = 0; q8 < 8; ++q8) { a1 += redA[tid][q8]; a2 += redB[tid][q8]; }
            float mu = a1 * (1.0f / D);
            float var = a2 * (1.0f / D) - mu * mu;
            stats[tid][0] = mu; stats[tid][1] = rsqrtf(var + EPS);
        }
        __syncthreads();
        #pragma unroll
        for (int nf = 0; nf < 2; ++nf) {
            int c = wv * 32 + nf * 16 + lr;
            float gg = ln_g[512 + c], bb = ln_b[512 + c];
            #pragma unroll
            for (int jj = 0; jj < 4; ++jj) {
                int ridx = qi * 4 + jj;
                float ov = (v[nf][jj] - stats[ridx][0]) * stats[ridx][1] * gg + bb;
                s2reg[nf][jj] = ov;
                Sb[ridx][c] = f2b(ov);
            }
        }
    }
    __syncthreads();

    // ---- P9: FF1 (Sb = S2) -> Hb ----
    {
        const unsigned short* W1T = wB + 524288;
        f32x4 acc[4] = {};
        #pragma unroll
        for (int kk = 0; kk < 256; kk += 32) {
            short8 a = *(const short8*)&Sb[lr][qi * 8 + kk];
            #pragma unroll
            for (int nf = 0; nf < 4; ++nf) {
                short8 b = *(const short8*)(W1T + (size_t)(wv * 64 + nf * 16 + lr) * 256 + qi * 8 + kk);
                acc[nf] = __builtin_amdgcn_mfma_f32_16x16x32_bf16(a, b, acc[nf], 0, 0, 0);
            }
        }
        #pragma unroll
        for (int nf = 0; nf < 4; ++nf) {
            int c = wv * 64 + nf * 16 + lr;
            float bc = ff_b1[c];
            #pragma unroll
            for (int jj = 0; jj < 4; ++jj)
                Hb[qi * 4 + jj][c] = f2b(fmaxf(acc[nf][jj] + bc, 0.0f));
        }
    }
    __syncthreads();

    // ---- P10: FF2 (K=512) + resid(s2reg) + LN1 + mask -> out ----
    {
        const unsigned short* W2T = wB + 655360;
        f32x4 acc[2] = {};
        #pragma unroll
        for (int kk = 0; kk < 512; kk += 32) {
            short8 a = *(const short8*)&Hb[lr][qi * 8 + kk];
            #pragma unroll
            for (int nf = 0; nf < 2; ++nf) {
                short8 b = *(const short8*)(W2T + (size_t)(wv * 32 + nf * 16 + lr) * 512 + qi * 8 + kk);
                acc[nf] = __builtin_amdgcn_mfma_f32_16x16x32_bf16(a, b, acc[nf], 0, 0, 0);
            }
        }
        float v[2][4], s1[4] = {0.f,0.f,0.f,0.f}, s2[4] = {0.f,0.f,0.f,0.f};
        #pragma unroll
        for (int nf = 0; nf < 2; ++nf) {
            int c = wv * 32 + nf * 16 + lr;
            float bc = ff_b2[c];
            #pragma unroll
            for (int jj = 0; jj < 4; ++jj) {
                float vv = acc[nf][jj] + bc + s2reg[nf][jj];
                v[nf][jj] = vv; s1[jj] += vv; s2[jj] += vv * vv;
            }
        }
        #pragma unroll
        for (int jj = 0; jj < 4; ++jj) {
            #pragma unroll
            for (int off = 1; off < 16; off <<= 1) {
                s1[jj] += __shfl_xor(s1[jj], off);
                s2[jj] += __shfl_xor(s2[jj], off);
            }
        }
        if (lr == 0) {
            #pragma unroll
            for (int jj = 0; jj < 4; ++jj) { redA[qi*4+jj][wv] = s1[jj]; redB[qi*4+jj][wv] = s2[jj]; }
        }
        __syncthreads();
        if (tid < 16) {
            float a1 = 0.f, a2 = 0.f;
            #pragma unroll
            for (int q8 = 0; q8 < 8; ++q8) { a1 += redA[tid][q8]; a2 += redB[tid][q8]; }
            float mu = a1 * (1.0f / D);
            float var = a2 * (1.0f / D) - mu * mu;
            stats[tid][0] = mu; stats[tid][1] = rsqrtf(var + EPS);
        }
        __syncthreads();
        bool arow_act[4];
        #pragma unroll
        for (int jj = 0; jj < 4; ++jj) {
            int row = n0 + qi * 4 + jj;
            arow_act[jj] = act_at(active, row >> 6, row & 63);
        }
        #pragma unroll
        for (int nf = 0; nf < 2; ++nf) {
            int c = wv * 32 + nf * 16 + lr;
            float gg = ln_g[256 + c], bb = ln_b[256 + c];
            #pragma unroll
            for (int jj = 0; jj < 4; ++jj) {
                int ridx = qi * 4 + jj;
                float ov = (v[nf][jj] - stats[ridx][0]) * stats[ridx][1] * gg + bb;
                out[(size_t)(n0 + ridx) * D + c] = arow_act[jj] ? ov : 0.0f;
            }
        }
        if (tid < 16) {
            int row = n0 + tid;
            out[(size_t)NND + row] = act_at(active, row >> 6, row & 63) ? 1.0f : 0.0f;
        }
    }
}

extern "C" void kernel_launch(void* const* d_in, const int* in_sizes, int n_in,
                              void* d_out, int out_size, void* d_ws, size_t ws_size,
                              hipStream_t stream) {
    const float* x       = (const float*)d_in[0];
    const float* memory  = (const float*)d_in[1];
    const int*   active  = (const int*)d_in[2];
    const float* attn_w  = (const float*)d_in[3];
    const float* attn_b  = (const float*)d_in[4];
    const float* pattn_w = (const float*)d_in[5];
    const float* pattn_b = (const float*)d_in[6];
    const float* ff_w1   = (const float*)d_in[7];
    const float* ff_b1   = (const float*)d_in[8];
    const float* ff_w2   = (const float*)d_in[9];
    const float* ff_b2   = (const float*)d_in[10];
    const float* ln_g    = (const float*)d_in[11];
    const float* ln_b    = (const float*)d_in[12];
    float* out = (float*)d_out;

    unsigned short* wsb = (unsigned short*)d_ws;
    unsigned short* xmB  = wsb;
    unsigned short* memB = wsb + (size_t)NND;
    unsigned short* wB   = wsb + 2 * (size_t)NND;               // 786432 shorts
    unsigned short* q1b  = wB + 786432;
    unsigned short* k1b  = q1b + (size_t)NND;
    unsigned short* v1b  = k1b + (size_t)NND;
    unsigned short* k2b  = v1b + (size_t)NND;                   // 4097 rows
    unsigned short* v2b  = k2b + (size_t)NND + 256;             // 4097 rows

    hipFuncSetAttribute(reinterpret_cast<const void*>(fused_kernel),
                        hipFuncAttributeMaxDynamicSharedMemorySize, SMEM_SZ);

    hipLaunchKernelGGL(prep_kernel, dim3(704), dim3(256), 0, stream,
                       x, memory, active, attn_w, pattn_w, ff_w1, ff_w2, pattn_b,
                       xmB, memB, wB, k2b + (size_t)NND, v2b + (size_t)NND);
    hipLaunchKernelGGL(proj_gemm, dim3(64, 20), dim3(256), 0, stream,
                       xmB, memB, wB, attn_b, pattn_b, q1b, k1b, v1b, k2b, v2b);
    hipLaunchKernelGGL(fused_kernel, dim3(256), dim3(512), SMEM_SZ, stream,
                       active, x, wB, attn_b, pattn_b, ff_b1, ff_b2, ln_g, ln_b,
                       q1b, k1b, v1b, k2b, v2b, out);
}

// Round 13
// 88.290 us; speedup vs baseline: 1.4615x; 1.0152x over previous
//
#include <hip/hip_runtime.h>
#include <math.h>

#define D 256
#define H2 512
#define HEADS 8
#define L 25
#define GH 64
#define GW 64
#define NN 4096
#define EPS 1e-5f
#define SCALE 0.17677669529663687f  // 1/sqrt(32)
#define NND 1048576                 // NN*D

typedef __attribute__((ext_vector_type(8))) short short8;
typedef __attribute__((ext_vector_type(4))) short short4v;
typedef __attribute__((ext_vector_type(4))) float f32x4;

__device__ __forceinline__ bool act_at(const int* __restrict__ active, int h, int w) {
    if (h < 0 || h >= GH || w < 0 || w >= GW) return false;
    if (h == 2 && w == 2) return false;   // ap.at[:, center, center].set(False) quirk
    return active[h * GW + w] != 0;
}

__device__ __forceinline__ unsigned short f2b(float f) {
    unsigned u = __float_as_uint(f);
    u += 0x7fffu + ((u >> 16) & 1u);      // RNE
    return (unsigned short)(u >> 16);
}
__device__ __forceinline__ float b2f(short v) {
    return __uint_as_float(((unsigned)(unsigned short)v) << 16);
}

// async global->LDS DMA, 16 B per lane; lds dest = wave-uniform base + lane*16
__device__ __forceinline__ void dma16(const unsigned short* g, unsigned short* l) {
    __builtin_amdgcn_global_load_lds(
        (const __attribute__((address_space(1))) unsigned int*)g,
        (__attribute__((address_space(3))) unsigned int*)l, 16, 0, 0);
}

// ---------------- prep: bf16 conversions + LDS-tiled weight transposes ----------------
__global__ __launch_bounds__(256)
void prep_kernel(const float* __restrict__ x, const float* __restrict__ mem,
                 const int* __restrict__ active,
                 const float* __restrict__ attn_w, const float* __restrict__ pattn_w,
                 const float* __restrict__ ff_w1, const float* __restrict__ ff_w2,
                 const float* __restrict__ pattn_b,
                 unsigned short* __restrict__ xmB, unsigned short* __restrict__ memB,
                 unsigned short* __restrict__ wB,
                 unsigned short* __restrict__ k2bias, unsigned short* __restrict__ v2bias) {
    const int tid = threadIdx.x;
    const int bid = blockIdx.x;
    if (bid < 192) {
        __shared__ float tile[64][65];
        const float* src; unsigned short* dst;
        int i0, n0, srcLen, dstLen;
        if (bid < 128) {
            int mat = bid >> 4, t16 = bid & 15;
            i0 = (t16 >> 2) * 64; n0 = (t16 & 3) * 64;
            src = (mat < 4) ? (attn_w + mat * 65536) : (pattn_w + (mat - 4) * 65536);
            dst = wB + mat * 65536;
            srcLen = 256; dstLen = 256;
        } else if (bid < 160) {
            int t = bid - 128;
            i0 = (t >> 3) * 64; n0 = (t & 7) * 64;
            src = ff_w1; dst = wB + 524288;      // W1T: [512][256]
            srcLen = 512; dstLen = 256;
        } else {
            int t = bid - 160;
            i0 = (t >> 2) * 64; n0 = (t & 3) * 64;
            src = ff_w2; dst = wB + 655360;      // W2T: [256][512]
            srcLen = 256; dstLen = 512;
        }
        int c = tid & 63, r4 = tid >> 6;
        for (int rr = 0; rr < 64; rr += 4)
            tile[rr + r4][c] = src[(size_t)(i0 + rr + r4) * srcLen + n0 + c];
        __syncthreads();
        for (int rr = 0; rr < 64; rr += 4) {
            int r = rr + r4;
            dst[(size_t)(n0 + r) * dstLen + i0 + c] = f2b(tile[c][r]);
        }
    } else {
        const int t0 = (bid - 192) * 256 + tid;
        for (int t = t0; t < 524800; t += 512 * 256) {
            if (t < 262144) {
                int n = t >> 6;
                bool a = act_at(active, n >> 6, n & 63);
                float4 v = ((const float4*)x)[t];
                ushort4 u;
                u.x = f2b(a ? v.x : 0.0f); u.y = f2b(a ? v.y : 0.0f);
                u.z = f2b(a ? v.z : 0.0f); u.w = f2b(a ? v.w : 0.0f);
                ((ushort4*)xmB)[t] = u;
            } else if (t < 524288) {
                int tt = t - 262144;
                float4 v = ((const float4*)mem)[tt];
                ushort4 u;
                u.x = f2b(v.x); u.y = f2b(v.y); u.z = f2b(v.z); u.w = f2b(v.w);
                ((ushort4*)memB)[tt] = u;
            } else {
                int tt = t - 524288;
                if (tt < 256) k2bias[tt] = f2b(pattn_b[256 + tt]);
                else          v2bias[tt - 256] = f2b(pattn_b[512 + (tt - 256)]);
            }
        }
    }
}

// ---------------- proj: 5 GEMM streams -> bf16 outputs ----------------
__global__ __launch_bounds__(256)
void proj_gemm(const unsigned short* __restrict__ xmB,
               const unsigned short* __restrict__ memB,
               const unsigned short* __restrict__ wB,
               const float* __restrict__ attn_b, const float* __restrict__ pattn_b,
               unsigned short* __restrict__ q1b, unsigned short* __restrict__ k1b,
               unsigned short* __restrict__ v1b, unsigned short* __restrict__ k2b,
               unsigned short* __restrict__ v2b) {
    const int s  = blockIdx.y >> 2;       // 0:Q1 1:K1 2:V1 3:K2 4:V2
    const int n0 = (blockIdx.y & 3) * 64;
    const unsigned short* A  = (s < 3) ? xmB : memB;
    const int wtIdx = (s < 3) ? s : (s + 2);            // K2->5, V2->6
    const unsigned short* WT = wB + (size_t)wtIdx * 65536;
    const float* bias = (s < 3) ? (attn_b + s * 256) : (pattn_b + (s - 2) * 256);
    unsigned short* outB;
    switch (s) { case 0: outB = q1b; break; case 1: outB = k1b; break;
                 case 2: outB = v1b; break; case 3: outB = k2b; break;
                 default: outB = v2b; }

    const int tid = threadIdx.x;
    const int wave = tid >> 6, lane = tid & 63;
    const int m0 = blockIdx.x * 64 + wave * 16;
    const int lr = lane & 15;
    const int lk = (lane >> 4) << 3;
    f32x4 acc[4] = {};
    const unsigned short* arow = A  + (size_t)(m0 + lr) * 256 + lk;
    const unsigned short* brow = WT + (size_t)(n0 + lr) * 256 + lk;
    #pragma unroll
    for (int kk = 0; kk < 256; kk += 32) {
        short8 a = *(const short8*)(arow + kk);
        #pragma unroll
        for (int nf = 0; nf < 4; ++nf) {
            short8 b = *(const short8*)(brow + (size_t)nf * 16 * 256 + kk);
            acc[nf] = __builtin_amdgcn_mfma_f32_16x16x32_bf16(a, b, acc[nf], 0, 0, 0);
        }
    }
    const int rbase = m0 + ((lane >> 4) << 2);
    #pragma unroll
    for (int nf = 0; nf < 4; ++nf) {
        int c = n0 + nf * 16 + lr;
        float bc = bias[c];
        #pragma unroll
        for (int jj = 0; jj < 4; ++jj)
            outB[(size_t)(rbase + jj) * 256 + c] = f2b(acc[nf][jj] + bc);
    }
}

// ---------------- dynamic LDS layout (151040 B) ----------------
#define BK_OFF   0            // K union: 100 x 256 bf16 = 51200
#define BV_OFF   51200        // V union: 51200
#define WGT_OFF  102400       // [16][8][25] f32 = 12800
#define T1B_OFF  115200       // [16][264] bf16 = 8448
#define SB_OFF   123648       // [16][264] bf16 = 8448
#define HB_OFF   132096       // [16][520] bf16 = 16640
#define ACT_OFF  148736       // 128
#define REDA_OFF 148864       // [16][16] f32 = 1024
#define REDB_OFF 149888       // 1024
#define STAT_OFF 150912       // 128
#define SMEM_SZ  151040

__device__ __forceinline__ int union_row(int c, int h, int w0, int fallback) {
    int u = c >> 5;
    int r = u / 20;
    int hh = h - 2 + r, ww = w0 - 2 + (u - r * 20);
    bool ib = ((unsigned)hh < GH) && ((unsigned)ww < GW);
    return ib ? ((hh << 6) | ww) : fallback;
}

// 3200 chunks over 1024 threads: k<4, tail (k=3) = 2 full waves
__device__ __forceinline__ void dma_union(const unsigned short* __restrict__ base,
                                          int h, int w0, int fallback,
                                          unsigned short* dstLds, int tid) {
    #pragma unroll
    for (int k = 0; k < 4; ++k) {
        int c = tid + k * 1024;
        if (c < 3200) {
            int row = union_row(c, h, w0, fallback);
            dma16(base + (size_t)row * 256 + (c & 31) * 8, dstLds + (size_t)c * 8);
        }
    }
}

// ---------------- fused chain kernel: 1024 threads, 16 waves ----------------
__global__ __launch_bounds__(1024)
void fused_kernel(const int* __restrict__ active, const float* __restrict__ x,
                  const unsigned short* __restrict__ wB,
                  const float* __restrict__ attn_b, const float* __restrict__ pattn_b,
                  const float* __restrict__ ff_b1, const float* __restrict__ ff_b2,
                  const float* __restrict__ ln_g, const float* __restrict__ ln_b,
                  const unsigned short* __restrict__ q1b,
                  const unsigned short* __restrict__ k1b,
                  const unsigned short* __restrict__ v1b,
                  const unsigned short* __restrict__ k2b,
                  const unsigned short* __restrict__ v2b,
                  float* __restrict__ out) {
    extern __shared__ __align__(16) char smem[];
    unsigned short (*bufK)[256] = (unsigned short(*)[256])(smem + BK_OFF);
    unsigned short (*bufV)[256] = (unsigned short(*)[256])(smem + BV_OFF);
    float (*wgt)[8][25]         = (float(*)[8][25])(smem + WGT_OFF);
    unsigned short (*T1b)[264]  = (unsigned short(*)[264])(smem + T1B_OFF);
    unsigned short (*Sb)[264]   = (unsigned short(*)[264])(smem + SB_OFF);
    unsigned short (*Hb)[520]   = (unsigned short(*)[520])(smem + HB_OFF);
    unsigned char* actU         = (unsigned char*)(smem + ACT_OFF);
    float (*redA)[16]           = (float(*)[16])(smem + REDA_OFF);
    float (*redB)[16]           = (float(*)[16])(smem + REDB_OFF);
    float (*stats)[2]           = (float(*)[2])(smem + STAT_OFF);

    const int tid = threadIdx.x;              // 1024 threads, 16 waves
    const int wv = tid >> 6, lane = tid & 63;
    const int lr = lane & 15, qi = lane >> 4;
    const int m = wv;                         // attn: wave wv owns node wv
    const int g8 = lane >> 3;                 // head
    const int bid = ((blockIdx.x & 7) << 5) | (blockIdx.x >> 3);   // XCD-chunked
    const int n0 = bid * 16;
    const int h = n0 >> 6, w0 = n0 & 63;

    // ---- P0: masks + K1/V1 unions via async DMA ----
    dma_union(k1b, h, w0, 0, (unsigned short*)(smem + BK_OFF), tid);
    dma_union(v1b, h, w0, 0, (unsigned short*)(smem + BV_OFF), tid);
    if (tid < 100) {
        int r = tid / 20;
        int hh = h - 2 + r, ww = w0 - 2 + (tid - r * 20);
        actU[tid] = act_at(active, hh, ww) ? 1 : 0;
    }
    __syncthreads();

    // ---- P1: attn1 scores (full wave per node; lane -> dims 4*lane..4*lane+3) ----
    {
        short4v qv = *(const short4v*)(q1b + (size_t)(n0 + m) * 256 + lane * 4);
        float q[4];
        #pragma unroll
        for (int j = 0; j < 4; ++j) q[j] = b2f(qv[j]);
        #pragma unroll 5
        for (int l = 0; l < L; ++l) {
            int u = (l / 5) * 20 + m + (l % 5);
            short4v kv = *(const short4v*)&bufK[u][lane * 4];
            float p = q[0] * b2f(kv[0]);
            #pragma unroll
            for (int j = 1; j < 4; ++j) p = fmaf(q[j], b2f(kv[j]), p);
            p += __shfl_xor(p, 1); p += __shfl_xor(p, 2); p += __shfl_xor(p, 4);
            float sv = actU[u] ? p * SCALE : -1e30f;
            if ((lane & 7) == 0) wgt[m][g8][l] = sv;
        }
    }
    __syncthreads();

    // ---- P2: issue K2 DMA into bufK (dead), then softmax1 ----
    dma_union(k2b, h, w0, NN, (unsigned short*)(smem + BK_OFF), tid);
    if (tid < 128) {
        int mm = tid >> 3, hd = tid & 7;
        float mx = -1e30f;
        for (int l = 0; l < L; ++l) mx = fmaxf(mx, wgt[mm][hd][l]);
        float sum = 0.0f;
        for (int l = 0; l < L; ++l) { float e = expf(wgt[mm][hd][l] - mx); wgt[mm][hd][l] = e; sum += e; }
        float inv = 1.0f / sum;
        for (int l = 0; l < L; ++l) wgt[mm][hd][l] *= inv;
    }
    __syncthreads();

    // ---- P3: PV1 (bufV = V1) -> T1b ----
    {
        float o[4] = {0.f, 0.f, 0.f, 0.f};
        #pragma unroll 5
        for (int l = 0; l < L; ++l) {
            int u = (l / 5) * 20 + m + (l % 5);
            if (actU[u]) {
                float wt = wgt[m][g8][l];
                short4v v4 = *(const short4v*)&bufV[u][lane * 4];
                #pragma unroll
                for (int j = 0; j < 4; ++j) o[j] = fmaf(wt, b2f(v4[j]), o[j]);
            }
        }
        unsigned short u8[4];
        #pragma unroll
        for (int j = 0; j < 4; ++j) u8[j] = f2b(o[j]);
        *(uint2*)&T1b[m][lane * 4] = *(uint2*)u8;
    }
    __syncthreads();

    // ---- P4: issue V2 DMA into bufV (dead); Wo1 + bias + resid(x) + LN0 ----
    float sreg[4];
    {
        dma_union(v2b, h, w0, NN, (unsigned short*)(smem + BV_OFF), tid);
        const unsigned short* Wo1T = wB + 3 * 65536;
        f32x4 acc = {};
        #pragma unroll
        for (int kk = 0; kk < 256; kk += 32) {
            short8 a = *(const short8*)&T1b[lr][qi * 8 + kk];
            short8 b = *(const short8*)(Wo1T + (size_t)(wv * 16 + lr) * 256 + qi * 8 + kk);
            acc = __builtin_amdgcn_mfma_f32_16x16x32_bf16(a, b, acc, 0, 0, 0);
        }
        const int c = wv * 16 + lr;
        float bc = attn_b[768 + c];
        float v[4], s1[4], s2[4];
        #pragma unroll
        for (int jj = 0; jj < 4; ++jj) {
            int row = n0 + qi * 4 + jj;
            float vv = acc[jj] + bc + x[(size_t)row * D + c];
            v[jj] = vv; s1[jj] = vv; s2[jj] = vv * vv;
        }
        #pragma unroll
        for (int jj = 0; jj < 4; ++jj) {
            #pragma unroll
            for (int off = 1; off < 16; off <<= 1) {
                s1[jj] += __shfl_xor(s1[jj], off);
                s2[jj] += __shfl_xor(s2[jj], off);
            }
        }
        if (lr == 0) {
            #pragma unroll
            for (int jj = 0; jj < 4; ++jj) { redA[qi*4+jj][wv] = s1[jj]; redB[qi*4+jj][wv] = s2[jj]; }
        }
        __syncthreads();
        if (tid < 16) {
            float a1 = 0.f, a2 = 0.f;
            #pragma unroll
            for (int q8 = 0; q8 < 16; ++q8) { a1 += redA[tid][q8]; a2 += redB[tid][q8]; }
            float mu = a1 * (1.0f / D);
            float var = a2 * (1.0f / D) - mu * mu;
            stats[tid][0] = mu; stats[tid][1] = rsqrtf(var + EPS);
        }
        __syncthreads();
        float gg = ln_g[c], bb = ln_b[c];
        #pragma unroll
        for (int jj = 0; jj < 4; ++jj) {
            int ridx = qi * 4 + jj;
            float ov = (v[jj] - stats[ridx][0]) * stats[ridx][1] * gg + bb;
            sreg[jj] = ov;
            Sb[ridx][c] = f2b(ov);
        }
    }
    __syncthreads();

    // ---- P5: Wq2 (Sb) -> T1b -> q2 regs ----
    float q2[4];
    {
        const unsigned short* Wq2T = wB + 4 * 65536;
        f32x4 acc = {};
        #pragma unroll
        for (int kk = 0; kk < 256; kk += 32) {
            short8 a = *(const short8*)&Sb[lr][qi * 8 + kk];
            short8 b = *(const short8*)(Wq2T + (size_t)(wv * 16 + lr) * 256 + qi * 8 + kk);
            acc = __builtin_amdgcn_mfma_f32_16x16x32_bf16(a, b, acc, 0, 0, 0);
        }
        const int c = wv * 16 + lr;
        float bc = pattn_b[c];
        #pragma unroll
        for (int jj = 0; jj < 4; ++jj)
            T1b[qi * 4 + jj][c] = f2b(acc[jj] + bc);
        __syncthreads();
        short4v qv = *(const short4v*)&T1b[m][lane * 4];
        #pragma unroll
        for (int j = 0; j < 4; ++j) q2[j] = b2f(qv[j]);
    }

    // ---- P6: attn2 scores (bufK = K2) ----
    #pragma unroll 5
    for (int l = 0; l < L; ++l) {
        int u = (l / 5) * 20 + m + (l % 5);
        short4v kv = *(const short4v*)&bufK[u][lane * 4];
        float p = q2[0] * b2f(kv[0]);
        #pragma unroll
        for (int j = 1; j < 4; ++j) p = fmaf(q2[j], b2f(kv[j]), p);
        p += __shfl_xor(p, 1); p += __shfl_xor(p, 2); p += __shfl_xor(p, 4);
        if ((lane & 7) == 0) wgt[m][g8][l] = p * SCALE;
    }
    __syncthreads();
    if (tid < 128) {
        int mm = tid >> 3, hd = tid & 7;
        float mx = -1e30f;
        for (int l = 0; l < L; ++l) mx = fmaxf(mx, wgt[mm][hd][l]);
        float sum = 0.0f;
        for (int l = 0; l < L; ++l) { float e = expf(wgt[mm][hd][l] - mx); wgt[mm][hd][l] = e; sum += e; }
        float inv = 1.0f / sum;
        for (int l = 0; l < L; ++l) wgt[mm][hd][l] *= inv;
    }
    __syncthreads();

    // ---- P7: PV2 (bufV = V2) -> T1b ----
    {
        float o[4] = {0.f, 0.f, 0.f, 0.f};
        #pragma unroll 5
        for (int l = 0; l < L; ++l) {
            int u = (l / 5) * 20 + m + (l % 5);
            float wt = wgt[m][g8][l];
            short4v v4 = *(const short4v*)&bufV[u][lane * 4];
            #pragma unroll
            for (int j = 0; j < 4; ++j) o[j] = fmaf(wt, b2f(v4[j]), o[j]);
        }
        unsigned short u8[4];
        #pragma unroll
        for (int j = 0; j < 4; ++j) u8[j] = f2b(o[j]);
        *(uint2*)&T1b[m][lane * 4] = *(uint2*)u8;
    }
    __syncthreads();

    // ---- P8: Wo2 + bias + resid(sreg) + LN2 -> s2reg + Sb ----
    float s2reg[4];
    {
        const unsigned short* Wo2T = wB + 7 * 65536;
        f32x4 acc = {};
        #pragma unroll
        for (int kk = 0; kk < 256; kk += 32) {
            short8 a = *(const short8*)&T1b[lr][qi * 8 + kk];
            short8 b = *(const short8*)(Wo2T + (size_t)(wv * 16 + lr) * 256 + qi * 8 + kk);
            acc = __builtin_amdgcn_mfma_f32_16x16x32_bf16(a, b, acc, 0, 0, 0);
        }
        const int c = wv * 16 + lr;
        float bc = pattn_b[768 + c];
        float v[4], s1[4], s2[4];
        #pragma unroll
        for (int jj = 0; jj < 4; ++jj) {
            float vv = acc[jj] + bc + sreg[jj];
            v[jj] = vv; s1[jj] = vv; s2[jj] = vv * vv;
        }
        #pragma unroll
        for (int jj = 0; jj < 4; ++jj) {
            #pragma unroll
            for (int off = 1; off < 16; off <<= 1) {
                s1[jj] += __shfl_xor(s1[jj], off);
                s2[jj] += __shfl_xor(s2[jj], off);
            }
        }
        if (lr == 0) {
            #pragma unroll
            for (int jj = 0; jj < 4; ++jj) { redA[qi*4+jj][wv] = s1[jj]; redB[qi*4+jj][wv] = s2[jj]; }
        }
        __syncthreads();
        if (tid < 16) {
            float a1 = 0.f, a2 = 0.f;
            #pragma unroll
            for (int q8 = 0; q8 < 16; ++q8) { a1 += redA[tid][q8]; a2 += redB[tid][q8]; }
            float mu = a1 * (1.0f / D);
            float var = a2 * (1.0f / D) - mu * mu;
            stats[tid][0] = mu; stats[tid][1] = rsqrtf(var + EPS);
        }
        __syncthreads();
        float gg = ln_g[512 + c], bb = ln_b[512 + c];
        #pragma unroll
        for (int jj = 0; jj < 4; ++jj) {
            int ridx = qi * 4 + jj;
            float ov = (v[jj] - stats[ridx][0]) * stats[ridx][1] * gg + bb;
            s2reg[jj] = ov;
            Sb[ridx][c] = f2b(ov);
        }
    }
    __syncthreads();

    // ---- P9: FF1 (Sb = S2) -> Hb (N=512: 16 waves x 32 cols) ----
    {
        const unsigned short* W1T = wB + 524288;
        f32x4 acc[2] = {};
        #pragma unroll
        for (int kk = 0; kk < 256; kk += 32) {
            short8 a = *(const short8*)&Sb[lr][qi * 8 + kk];
            #pragma unroll
            for (int nf = 0; nf < 2; ++nf) {
                short8 b = *(const short8*)(W1T + (size_t)(wv * 32 + nf * 16 + lr) * 256 + qi * 8 + kk);
                acc[nf] = __builtin_amdgcn_mfma_f32_16x16x32_bf16(a, b, acc[nf], 0, 0, 0);
            }
        }
        #pragma unroll
        for (int nf = 0; nf < 2; ++nf) {
            int c = wv * 32 + nf * 16 + lr;
            float bc = ff_b1[c];
            #pragma unroll
            for (int jj = 0; jj < 4; ++jj)
                Hb[qi * 4 + jj][c] = f2b(fmaxf(acc[nf][jj] + bc, 0.0f));
        }
    }
    __syncthreads();

    // ---- P10: FF2 (K=512) + resid(s2reg) + LN1 + mask -> out ----
    {
        const unsigned short* W2T = wB + 655360;
        f32x4 acc = {};
        #pragma unroll
        for (int kk = 0; kk < 512; kk += 32) {
            short8 a = *(const short8*)&Hb[lr][qi * 8 + kk];
            short8 b = *(const short8*)(W2T + (size_t)(wv * 16 + lr) * 512 + qi * 8 + kk);
            acc = __builtin_amdgcn_mfma_f32_16x16x32_bf16(a, b, acc, 0, 0, 0);
        }
        const int c = wv * 16 + lr;
        float bc = ff_b2[c];
        float v[4], s1[4], s2[4];
        #pragma unroll
        for (int jj = 0; jj < 4; ++jj) {
            float vv = acc[jj] + bc + s2reg[jj];
            v[jj] = vv; s1[jj] = vv; s2[jj] = vv * vv;
        }
        #pragma unroll
        for (int jj = 0; jj < 4; ++jj) {
            #pragma unroll
            for (int off = 1; off < 16; off <<= 1) {
                s1[jj] += __shfl_xor(s1[jj], off);
                s2[jj] += __shfl_xor(s2[jj], off);
            }
        }
        if (lr == 0) {
            #pragma unroll
            for (int jj = 0; jj < 4; ++jj) { redA[qi*4+jj][wv] = s1[jj]; redB[qi*4+jj][wv] = s2[jj]; }
        }
        __syncthreads();
        if (tid < 16) {
            float a1 = 0.f, a2 = 0.f;
            #pragma unroll
            for (int q8 = 0; q8 < 16; ++q8) { a1 += redA[tid][q8]; a2 += redB[tid][q8]; }
            float mu = a1 * (1.0f / D);
            float var = a2 * (1.0f / D) - mu * mu;
            stats[tid][0] = mu; stats[tid][1] = rsqrtf(var + EPS);
        }
        __syncthreads();
        bool arow_act[4];
        #pragma unroll
        for (int jj = 0; jj < 4; ++jj) {
            int row = n0 + qi * 4 + jj;
            arow_act[jj] = act_at(active, row >> 6, row & 63);
        }
        float gg = ln_g[256 + c], bb = ln_b[256 + c];
        #pragma unroll
        for (int jj = 0; jj < 4; ++jj) {
            int ridx = qi * 4 + jj;
            float ov = (v[jj] - stats[ridx][0]) * stats[ridx][1] * gg + bb;
            out[(size_t)(n0 + ridx) * D + c] = arow_act[jj] ? ov : 0.0f;
        }
        if (tid < 16) {
            int row = n0 + tid;
            out[(size_t)NND + row] = act_at(active, row >> 6, row & 63) ? 1.0f : 0.0f;
        }
    }
}

extern "C" void kernel_launch(void* const* d_in, const int* in_sizes, int n_in,
                              void* d_out, int out_size, void* d_ws, size_t ws_size,
                              hipStream_t stream) {
    const float* x       = (const float*)d_in[0];
    const float* memory  = (const float*)d_in[1];
    const int*   active  = (const int*)d_in[2];
    const float* attn_w  = (const float*)d_in[3];
    const float* attn_b  = (const float*)d_in[4];
    const float* pattn_w = (const float*)d_in[5];
    const float* pattn_b = (const float*)d_in[6];
    const float* ff_w1   = (const float*)d_in[7];
    const float* ff_b1   = (const float*)d_in[8];
    const float* ff_w2   = (const float*)d_in[9];
    const float* ff_b2   = (const float*)d_in[10];
    const float* ln_g    = (const float*)d_in[11];
    const float* ln_b    = (const float*)d_in[12];
    float* out = (float*)d_out;

    unsigned short* wsb = (unsigned short*)d_ws;
    unsigned short* xmB  = wsb;
    unsigned short* memB = wsb + (size_t)NND;
    unsigned short* wB   = wsb + 2 * (size_t)NND;               // 786432 shorts
    unsigned short* q1b  = wB + 786432;
    unsigned short* k1b  = q1b + (size_t)NND;
    unsigned short* v1b  = k1b + (size_t)NND;
    unsigned short* k2b  = v1b + (size_t)NND;                   // 4097 rows
    unsigned short* v2b  = k2b + (size_t)NND + 256;             // 4097 rows

    hipFuncSetAttribute(reinterpret_cast<const void*>(fused_kernel),
                        hipFuncAttributeMaxDynamicSharedMemorySize, SMEM_SZ);

    hipLaunchKernelGGL(prep_kernel, dim3(704), dim3(256), 0, stream,
                       x, memory, active, attn_w, pattn_w, ff_w1, ff_w2, pattn_b,
                       xmB, memB, wB, k2b + (size_t)NND, v2b + (size_t)NND);
    hipLaunchKernelGGL(proj_gemm, dim3(64, 20), dim3(256), 0, stream,
                       xmB, memB, wB, attn_b, pattn_b, q1b, k1b, v1b, k2b, v2b);
    hipLaunchKernelGGL(fused_kernel, dim3(256), dim3(1024), SMEM_SZ, stream,
                       active, x, wB, attn_b, pattn_b, ff_b1, ff_b2, ln_g, ln_b,
                       q1b, k1b, v1b, k2b, v2b, out);
}

// Round 14
// 85.996 us; speedup vs baseline: 1.5005x; 1.0267x over previous
//
#include <hip/hip_runtime.h>
#include <math.h>

#define D 256
#define H2 512
#define HEADS 8
#define L 25
#define GH 64
#define GW 64
#define NN 4096
#define EPS 1e-5f
#define SCALE 0.17677669529663687f  // 1/sqrt(32)
#define NND 1048576                 // NN*D

typedef __attribute__((ext_vector_type(8))) short short8;
typedef __attribute__((ext_vector_type(4))) short short4v;
typedef __attribute__((ext_vector_type(4))) float f32x4;

__device__ __forceinline__ bool act_at(const int* __restrict__ active, int h, int w) {
    if (h < 0 || h >= GH || w < 0 || w >= GW) return false;
    if (h == 2 && w == 2) return false;   // ap.at[:, center, center].set(False) quirk
    return active[h * GW + w] != 0;
}

__device__ __forceinline__ unsigned short f2b(float f) {
    unsigned u = __float_as_uint(f);
    u += 0x7fffu + ((u >> 16) & 1u);      // RNE
    return (unsigned short)(u >> 16);
}
__device__ __forceinline__ float b2f(short v) {
    return __uint_as_float(((unsigned)(unsigned short)v) << 16);
}

// async global->LDS DMA, 16 B per lane; lds dest = wave-uniform base + lane*16
__device__ __forceinline__ void dma16(const unsigned short* g, unsigned short* l) {
    __builtin_amdgcn_global_load_lds(
        (const __attribute__((address_space(1))) unsigned int*)g,
        (__attribute__((address_space(3))) unsigned int*)l, 16, 0, 0);
}

// ---------------- prep: bf16 conversions + LDS-tiled weight transposes ----------------
__global__ __launch_bounds__(256)
void prep_kernel(const float* __restrict__ x, const float* __restrict__ mem,
                 const int* __restrict__ active,
                 const float* __restrict__ attn_w, const float* __restrict__ pattn_w,
                 const float* __restrict__ ff_w1, const float* __restrict__ ff_w2,
                 const float* __restrict__ pattn_b,
                 unsigned short* __restrict__ xmB, unsigned short* __restrict__ memB,
                 unsigned short* __restrict__ wB,
                 unsigned short* __restrict__ k2bias, unsigned short* __restrict__ v2bias) {
    const int tid = threadIdx.x;
    const int bid = blockIdx.x;
    if (bid < 192) {
        __shared__ float tile[64][65];
        const float* src; unsigned short* dst;
        int i0, n0, srcLen, dstLen;
        if (bid < 128) {
            int mat = bid >> 4, t16 = bid & 15;
            i0 = (t16 >> 2) * 64; n0 = (t16 & 3) * 64;
            src = (mat < 4) ? (attn_w + mat * 65536) : (pattn_w + (mat - 4) * 65536);
            dst = wB + mat * 65536;
            srcLen = 256; dstLen = 256;
        } else if (bid < 160) {
            int t = bid - 128;
            i0 = (t >> 3) * 64; n0 = (t & 7) * 64;
            src = ff_w1; dst = wB + 524288;      // W1T: [512][256]
            srcLen = 512; dstLen = 256;
        } else {
            int t = bid - 160;
            i0 = (t >> 2) * 64; n0 = (t & 3) * 64;
            src = ff_w2; dst = wB + 655360;      // W2T: [256][512]
            srcLen = 256; dstLen = 512;
        }
        int c = tid & 63, r4 = tid >> 6;
        for (int rr = 0; rr < 64; rr += 4)
            tile[rr + r4][c] = src[(size_t)(i0 + rr + r4) * srcLen + n0 + c];
        __syncthreads();
        for (int rr = 0; rr < 64; rr += 4) {
            int r = rr + r4;
            dst[(size_t)(n0 + r) * dstLen + i0 + c] = f2b(tile[c][r]);
        }
    } else {
        const int t0 = (bid - 192) * 256 + tid;
        for (int t = t0; t < 524800; t += 512 * 256) {
            if (t < 262144) {
                int n = t >> 6;
                bool a = act_at(active, n >> 6, n & 63);
                float4 v = ((const float4*)x)[t];
                ushort4 u;
                u.x = f2b(a ? v.x : 0.0f); u.y = f2b(a ? v.y : 0.0f);
                u.z = f2b(a ? v.z : 0.0f); u.w = f2b(a ? v.w : 0.0f);
                ((ushort4*)xmB)[t] = u;
            } else if (t < 524288) {
                int tt = t - 262144;
                float4 v = ((const float4*)mem)[tt];
                ushort4 u;
                u.x = f2b(v.x); u.y = f2b(v.y); u.z = f2b(v.z); u.w = f2b(v.w);
                ((ushort4*)memB)[tt] = u;
            } else {
                int tt = t - 524288;
                if (tt < 256) k2bias[tt] = f2b(pattn_b[256 + tt]);
                else          v2bias[tt - 256] = f2b(pattn_b[512 + (tt - 256)]);
            }
        }
    }
}

// ---------------- proj: 5 GEMM streams -> bf16 outputs ----------------
__global__ __launch_bounds__(256)
void proj_gemm(const unsigned short* __restrict__ xmB,
               const unsigned short* __restrict__ memB,
               const unsigned short* __restrict__ wB,
               const float* __restrict__ attn_b, const float* __restrict__ pattn_b,
               unsigned short* __restrict__ q1b, unsigned short* __restrict__ k1b,
               unsigned short* __restrict__ v1b, unsigned short* __restrict__ k2b,
               unsigned short* __restrict__ v2b) {
    const int s  = blockIdx.y >> 2;       // 0:Q1 1:K1 2:V1 3:K2 4:V2
    const int n0 = (blockIdx.y & 3) * 64;
    const unsigned short* A  = (s < 3) ? xmB : memB;
    const int wtIdx = (s < 3) ? s : (s + 2);            // K2->5, V2->6
    const unsigned short* WT = wB + (size_t)wtIdx * 65536;
    const float* bias = (s < 3) ? (attn_b + s * 256) : (pattn_b + (s - 2) * 256);
    unsigned short* outB;
    switch (s) { case 0: outB = q1b; break; case 1: outB = k1b; break;
                 case 2: outB = v1b; break; case 3: outB = k2b; break;
                 default: outB = v2b; }

    const int tid = threadIdx.x;
    const int wave = tid >> 6, lane = tid & 63;
    const int m0 = blockIdx.x * 64 + wave * 16;
    const int lr = lane & 15;
    const int lk = (lane >> 4) << 3;
    f32x4 acc[4] = {};
    const unsigned short* arow = A  + (size_t)(m0 + lr) * 256 + lk;
    const unsigned short* brow = WT + (size_t)(n0 + lr) * 256 + lk;
    #pragma unroll
    for (int kk = 0; kk < 256; kk += 32) {
        short8 a = *(const short8*)(arow + kk);
        #pragma unroll
        for (int nf = 0; nf < 4; ++nf) {
            short8 b = *(const short8*)(brow + (size_t)nf * 16 * 256 + kk);
            acc[nf] = __builtin_amdgcn_mfma_f32_16x16x32_bf16(a, b, acc[nf], 0, 0, 0);
        }
    }
    const int rbase = m0 + ((lane >> 4) << 2);
    #pragma unroll
    for (int nf = 0; nf < 4; ++nf) {
        int c = n0 + nf * 16 + lr;
        float bc = bias[c];
        #pragma unroll
        for (int jj = 0; jj < 4; ++jj)
            outB[(size_t)(rbase + jj) * 256 + c] = f2b(acc[nf][jj] + bc);
    }
}

// ---------------- dynamic LDS layout (138240 B) ----------------
#define BK_OFF   0            // K union: 100 x 256 bf16 = 51200
#define BV_OFF   51200        // V union: 51200
#define T1B_OFF  102400       // [16][264] bf16 = 8448
#define SB_OFF   110848       // [16][264] bf16 = 8448
#define HB_OFF   119296       // [16][520] bf16 = 16640
#define ACT_OFF  135936       // 128
#define REDA_OFF 136064       // [16][16] f32 = 1024
#define REDB_OFF 137088       // 1024
#define STAT_OFF 138112       // 128
#define SMEM_SZ  138240

__device__ __forceinline__ int union_row(int c, int h, int w0, int fallback) {
    int u = c >> 5;
    int r = u / 20;
    int hh = h - 2 + r, ww = w0 - 2 + (u - r * 20);
    bool ib = ((unsigned)hh < GH) && ((unsigned)ww < GW);
    return ib ? ((hh << 6) | ww) : fallback;
}

// 3200 chunks over 1024 threads: k<4, tail (k=3) = 2 full waves
__device__ __forceinline__ void dma_union(const unsigned short* __restrict__ base,
                                          int h, int w0, int fallback,
                                          unsigned short* dstLds, int tid) {
    #pragma unroll
    for (int k = 0; k < 4; ++k) {
        int c = tid + k * 1024;
        if (c < 3200) {
            int row = union_row(c, h, w0, fallback);
            dma16(base + (size_t)row * 256 + (c & 31) * 8, dstLds + (size_t)c * 8);
        }
    }
}

// ---------------- fused chain kernel: 1024 threads, 16 waves ----------------
__global__ __launch_bounds__(1024)
void fused_kernel(const int* __restrict__ active, const float* __restrict__ x,
                  const unsigned short* __restrict__ wB,
                  const float* __restrict__ attn_b, const float* __restrict__ pattn_b,
                  const float* __restrict__ ff_b1, const float* __restrict__ ff_b2,
                  const float* __restrict__ ln_g, const float* __restrict__ ln_b,
                  const unsigned short* __restrict__ q1b,
                  const unsigned short* __restrict__ k1b,
                  const unsigned short* __restrict__ v1b,
                  const unsigned short* __restrict__ k2b,
                  const unsigned short* __restrict__ v2b,
                  float* __restrict__ out) {
    extern __shared__ __align__(16) char smem[];
    unsigned short (*bufK)[256] = (unsigned short(*)[256])(smem + BK_OFF);
    unsigned short (*bufV)[256] = (unsigned short(*)[256])(smem + BV_OFF);
    unsigned short (*T1b)[264]  = (unsigned short(*)[264])(smem + T1B_OFF);
    unsigned short (*Sb)[264]   = (unsigned short(*)[264])(smem + SB_OFF);
    unsigned short (*Hb)[520]   = (unsigned short(*)[520])(smem + HB_OFF);
    unsigned char* actU         = (unsigned char*)(smem + ACT_OFF);
    float (*redA)[16]           = (float(*)[16])(smem + REDA_OFF);
    float (*redB)[16]           = (float(*)[16])(smem + REDB_OFF);
    float (*stats)[2]           = (float(*)[2])(smem + STAT_OFF);

    const int tid = threadIdx.x;              // 1024 threads, 16 waves
    const int wv = tid >> 6, lane = tid & 63;
    const int lr = lane & 15, qi = lane >> 4;
    const int m = wv;                         // attn: wave wv owns node wv
    const int bid = ((blockIdx.x & 7) << 5) | (blockIdx.x >> 3);   // XCD-chunked
    const int n0 = bid * 16;
    const int h = n0 >> 6, w0 = n0 & 63;

    // ---- P0: masks + K1/V1 unions via async DMA ----
    dma_union(k1b, h, w0, 0, (unsigned short*)(smem + BK_OFF), tid);
    dma_union(v1b, h, w0, 0, (unsigned short*)(smem + BV_OFF), tid);
    if (tid < 100) {
        int r = tid / 20;
        int hh = h - 2 + r, ww = w0 - 2 + (tid - r * 20);
        actU[tid] = act_at(active, hh, ww) ? 1 : 0;
    }
    __syncthreads();

    // ---- A1: scores + in-register softmax + PV (barrier-free, wave-local) ----
    {
        float q[4];
        {
            short4v qv = *(const short4v*)(q1b + (size_t)(n0 + m) * 256 + lane * 4);
            #pragma unroll
            for (int j = 0; j < 4; ++j) q[j] = b2f(qv[j]);
        }
        float sc[L];
        #pragma unroll
        for (int l = 0; l < L; ++l) {
            int u = (l / 5) * 20 + m + (l % 5);
            short4v kv = *(const short4v*)&bufK[u][lane * 4];
            float p = q[0] * b2f(kv[0]);
            #pragma unroll
            for (int j = 1; j < 4; ++j) p = fmaf(q[j], b2f(kv[j]), p);
            p += __shfl_xor(p, 1); p += __shfl_xor(p, 2); p += __shfl_xor(p, 4);
            sc[l] = actU[u] ? p * SCALE : -1e30f;
        }
        float mx = sc[0];
        #pragma unroll
        for (int l = 1; l < L; ++l) mx = fmaxf(mx, sc[l]);
        float sum = 0.0f;
        #pragma unroll
        for (int l = 0; l < L; ++l) { sc[l] = expf(sc[l] - mx); sum += sc[l]; }
        float inv = 1.0f / sum;
        float o[4] = {0.f, 0.f, 0.f, 0.f};
        #pragma unroll
        for (int l = 0; l < L; ++l) {
            int u = (l / 5) * 20 + m + (l % 5);
            short4v v4 = *(const short4v*)&bufV[u][lane * 4];
            #pragma unroll
            for (int j = 0; j < 4; ++j) o[j] = fmaf(sc[l], b2f(v4[j]), o[j]);
        }
        unsigned short u8[4];
        #pragma unroll
        for (int j = 0; j < 4; ++j) u8[j] = f2b(o[j] * inv);
        *(uint2*)&T1b[m][lane * 4] = *(uint2*)u8;
    }
    __syncthreads();   // B2: T1b ready; bufK/bufV dead

    // ---- P4: issue K2/V2 DMA; Wo1 + bias + resid(x) + LN0 -> sreg + Sb ----
    float sreg[4];
    {
        dma_union(k2b, h, w0, NN, (unsigned short*)(smem + BK_OFF), tid);
        dma_union(v2b, h, w0, NN, (unsigned short*)(smem + BV_OFF), tid);
        const unsigned short* Wo1T = wB + 3 * 65536;
        f32x4 acc = {};
        #pragma unroll
        for (int kk = 0; kk < 256; kk += 32) {
            short8 a = *(const short8*)&T1b[lr][qi * 8 + kk];
            short8 b = *(const short8*)(Wo1T + (size_t)(wv * 16 + lr) * 256 + qi * 8 + kk);
            acc = __builtin_amdgcn_mfma_f32_16x16x32_bf16(a, b, acc, 0, 0, 0);
        }
        const int c = wv * 16 + lr;
        float bc = attn_b[768 + c];
        float v[4], s1[4], s2[4];
        #pragma unroll
        for (int jj = 0; jj < 4; ++jj) {
            int row = n0 + qi * 4 + jj;
            float vv = acc[jj] + bc + x[(size_t)row * D + c];
            v[jj] = vv; s1[jj] = vv; s2[jj] = vv * vv;
        }
        #pragma unroll
        for (int jj = 0; jj < 4; ++jj) {
            #pragma unroll
            for (int off = 1; off < 16; off <<= 1) {
                s1[jj] += __shfl_xor(s1[jj], off);
                s2[jj] += __shfl_xor(s2[jj], off);
            }
        }
        if (lr == 0) {
            #pragma unroll
            for (int jj = 0; jj < 4; ++jj) { redA[qi*4+jj][wv] = s1[jj]; redB[qi*4+jj][wv] = s2[jj]; }
        }
        __syncthreads();
        if (tid < 16) {
            float a1 = 0.f, a2 = 0.f;
            #pragma unroll
            for (int q8 = 0; q8 < 16; ++q8) { a1 += redA[tid][q8]; a2 += redB[tid][q8]; }
            float mu = a1 * (1.0f / D);
            float var = a2 * (1.0f / D) - mu * mu;
            stats[tid][0] = mu; stats[tid][1] = rsqrtf(var + EPS);
        }
        __syncthreads();
        float gg = ln_g[c], bb = ln_b[c];
        #pragma unroll
        for (int jj = 0; jj < 4; ++jj) {
            int ridx = qi * 4 + jj;
            float ov = (v[jj] - stats[ridx][0]) * stats[ridx][1] * gg + bb;
            sreg[jj] = ov;
            Sb[ridx][c] = f2b(ov);
        }
    }
    __syncthreads();

    // ---- P5: Wq2 (Sb) -> T1b -> q2 regs ----
    float q2[4];
    {
        const unsigned short* Wq2T = wB + 4 * 65536;
        f32x4 acc = {};
        #pragma unroll
        for (int kk = 0; kk < 256; kk += 32) {
            short8 a = *(const short8*)&Sb[lr][qi * 8 + kk];
            short8 b = *(const short8*)(Wq2T + (size_t)(wv * 16 + lr) * 256 + qi * 8 + kk);
            acc = __builtin_amdgcn_mfma_f32_16x16x32_bf16(a, b, acc, 0, 0, 0);
        }
        const int c = wv * 16 + lr;
        float bc = pattn_b[c];
        #pragma unroll
        for (int jj = 0; jj < 4; ++jj)
            T1b[qi * 4 + jj][c] = f2b(acc[jj] + bc);
        __syncthreads();
        short4v qv = *(const short4v*)&T1b[m][lane * 4];
        #pragma unroll
        for (int j = 0; j < 4; ++j) q2[j] = b2f(qv[j]);
    }
    // (no barrier: wave m only overwrites its own T1b row m below)

    // ---- A2: scores + in-register softmax + PV (bufK=K2, bufV=V2) ----
    {
        float sc[L];
        #pragma unroll
        for (int l = 0; l < L; ++l) {
            int u = (l / 5) * 20 + m + (l % 5);
            short4v kv = *(const short4v*)&bufK[u][lane * 4];
            float p = q2[0] * b2f(kv[0]);
            #pragma unroll
            for (int j = 1; j < 4; ++j) p = fmaf(q2[j], b2f(kv[j]), p);
            p += __shfl_xor(p, 1); p += __shfl_xor(p, 2); p += __shfl_xor(p, 4);
            sc[l] = p * SCALE;
        }
        float mx = sc[0];
        #pragma unroll
        for (int l = 1; l < L; ++l) mx = fmaxf(mx, sc[l]);
        float sum = 0.0f;
        #pragma unroll
        for (int l = 0; l < L; ++l) { sc[l] = expf(sc[l] - mx); sum += sc[l]; }
        float inv = 1.0f / sum;
        float o[4] = {0.f, 0.f, 0.f, 0.f};
        #pragma unroll
        for (int l = 0; l < L; ++l) {
            int u = (l / 5) * 20 + m + (l % 5);
            short4v v4 = *(const short4v*)&bufV[u][lane * 4];
            #pragma unroll
            for (int j = 0; j < 4; ++j) o[j] = fmaf(sc[l], b2f(v4[j]), o[j]);
        }
        unsigned short u8[4];
        #pragma unroll
        for (int j = 0; j < 4; ++j) u8[j] = f2b(o[j] * inv);
        *(uint2*)&T1b[m][lane * 4] = *(uint2*)u8;
    }
    __syncthreads();

    // ---- P8: Wo2 + bias + resid(sreg) + LN2 -> s2reg + Sb ----
    float s2reg[4];
    {
        const unsigned short* Wo2T = wB + 7 * 65536;
        f32x4 acc = {};
        #pragma unroll
        for (int kk = 0; kk < 256; kk += 32) {
            short8 a = *(const short8*)&T1b[lr][qi * 8 + kk];
            short8 b = *(const short8*)(Wo2T + (size_t)(wv * 16 + lr) * 256 + qi * 8 + kk);
            acc = __builtin_amdgcn_mfma_f32_16x16x32_bf16(a, b, acc, 0, 0, 0);
        }
        const int c = wv * 16 + lr;
        float bc = pattn_b[768 + c];
        float v[4], s1[4], s2[4];
        #pragma unroll
        for (int jj = 0; jj < 4; ++jj) {
            float vv = acc[jj] + bc + sreg[jj];
            v[jj] = vv; s1[jj] = vv; s2[jj] = vv * vv;
        }
        #pragma unroll
        for (int jj = 0; jj < 4; ++jj) {
            #pragma unroll
            for (int off = 1; off < 16; off <<= 1) {
                s1[jj] += __shfl_xor(s1[jj], off);
                s2[jj] += __shfl_xor(s2[jj], off);
            }
        }
        if (lr == 0) {
            #pragma unroll
            for (int jj = 0; jj < 4; ++jj) { redA[qi*4+jj][wv] = s1[jj]; redB[qi*4+jj][wv] = s2[jj]; }
        }
        __syncthreads();
        if (tid < 16) {
            float a1 = 0.f, a2 = 0.f;
            #pragma unroll
            for (int q8 = 0; q8 < 16; ++q8) { a1 += redA[tid][q8]; a2 += redB[tid][q8]; }
            float mu = a1 * (1.0f / D);
            float var = a2 * (1.0f / D) - mu * mu;
            stats[tid][0] = mu; stats[tid][1] = rsqrtf(var + EPS);
        }
        __syncthreads();
        float gg = ln_g[512 + c], bb = ln_b[512 + c];
        #pragma unroll
        for (int jj = 0; jj < 4; ++jj) {
            int ridx = qi * 4 + jj;
            float ov = (v[jj] - stats[ridx][0]) * stats[ridx][1] * gg + bb;
            s2reg[jj] = ov;
            Sb[ridx][c] = f2b(ov);
        }
    }
    __syncthreads();

    // ---- P9: FF1 (Sb = S2) -> Hb (N=512: 16 waves x 32 cols) ----
    {
        const unsigned short* W1T = wB + 524288;
        f32x4 acc[2] = {};
        #pragma unroll
        for (int kk = 0; kk < 256; kk += 32) {
            short8 a = *(const short8*)&Sb[lr][qi * 8 + kk];
            #pragma unroll
            for (int nf = 0; nf < 2; ++nf) {
                short8 b = *(const short8*)(W1T + (size_t)(wv * 32 + nf * 16 + lr) * 256 + qi * 8 + kk);
                acc[nf] = __builtin_amdgcn_mfma_f32_16x16x32_bf16(a, b, acc[nf], 0, 0, 0);
            }
        }
        #pragma unroll
        for (int nf = 0; nf < 2; ++nf) {
            int c = wv * 32 + nf * 16 + lr;
            float bc = ff_b1[c];
            #pragma unroll
            for (int jj = 0; jj < 4; ++jj)
                Hb[qi * 4 + jj][c] = f2b(fmaxf(acc[nf][jj] + bc, 0.0f));
        }
    }
    __syncthreads();

    // ---- P10: FF2 (K=512) + resid(s2reg) + LN1 + mask -> out ----
    {
        const unsigned short* W2T = wB + 655360;
        f32x4 acc = {};
        #pragma unroll
        for (int kk = 0; kk < 512; kk += 32) {
            short8 a = *(const short8*)&Hb[lr][qi * 8 + kk];
            short8 b = *(const short8*)(W2T + (size_t)(wv * 16 + lr) * 512 + qi * 8 + kk);
            acc = __builtin_amdgcn_mfma_f32_16x16x32_bf16(a, b, acc, 0, 0, 0);
        }
        const int c = wv * 16 + lr;
        float bc = ff_b2[c];
        float v[4], s1[4], s2[4];
        #pragma unroll
        for (int jj = 0; jj < 4; ++jj) {
            float vv = acc[jj] + bc + s2reg[jj];
            v[jj] = vv; s1[jj] = vv; s2[jj] = vv * vv;
        }
        #pragma unroll
        for (int jj = 0; jj < 4; ++jj) {
            #pragma unroll
            for (int off = 1; off < 16; off <<= 1) {
                s1[jj] += __shfl_xor(s1[jj], off);
                s2[jj] += __shfl_xor(s2[jj], off);
            }
        }
        if (lr == 0) {
            #pragma unroll
            for (int jj = 0; jj < 4; ++jj) { redA[qi*4+jj][wv] = s1[jj]; redB[qi*4+jj][wv] = s2[jj]; }
        }
        __syncthreads();
        if (tid < 16) {
            float a1 = 0.f, a2 = 0.f;
            #pragma unroll
            for (int q8 = 0; q8 < 16; ++q8) { a1 += redA[tid][q8]; a2 += redB[tid][q8]; }
            float mu = a1 * (1.0f / D);
            float var = a2 * (1.0f / D) - mu * mu;
            stats[tid][0] = mu; stats[tid][1] = rsqrtf(var + EPS);
        }
        __syncthreads();
        bool arow_act[4];
        #pragma unroll
        for (int jj = 0; jj < 4; ++jj) {
            int row = n0 + qi * 4 + jj;
            arow_act[jj] = act_at(active, row >> 6, row & 63);
        }
        float gg = ln_g[256 + c], bb = ln_b[256 + c];
        #pragma unroll
        for (int jj = 0; jj < 4; ++jj) {
            int ridx = qi * 4 + jj;
            float ov = (v[jj] - stats[ridx][0]) * stats[ridx][1] * gg + bb;
            out[(size_t)(n0 + ridx) * D + c] = arow_act[jj] ? ov : 0.0f;
        }
        if (tid < 16) {
            int row = n0 + tid;
            out[(size_t)NND + row] = act_at(active, row >> 6, row & 63) ? 1.0f : 0.0f;
        }
    }
}

extern "C" void kernel_launch(void* const* d_in, const int* in_sizes, int n_in,
                              void* d_out, int out_size, void* d_ws, size_t ws_size,
                              hipStream_t stream) {
    const float* x       = (const float*)d_in[0];
    const float* memory  = (const float*)d_in[1];
    const int*   active  = (const int*)d_in[2];
    const float* attn_w  = (const float*)d_in[3];
    const float* attn_b  = (const float*)d_in[4];
    const float* pattn_w = (const float*)d_in[5];
    const float* pattn_b = (const float*)d_in[6];
    const float* ff_w1   = (const float*)d_in[7];
    const float* ff_b1   = (const float*)d_in[8];
    const float* ff_w2   = (const float*)d_in[9];
    const float* ff_b2   = (const float*)d_in[10];
    const float* ln_g    = (const float*)d_in[11];
    const float* ln_b    = (const float*)d_in[12];
    float* out = (float*)d_out;

    unsigned short* wsb = (unsigned short*)d_ws;
    unsigned short* xmB  = wsb;
    unsigned short* memB = wsb + (size_t)NND;
    unsigned short* wB   = wsb + 2 * (size_t)NND;               // 786432 shorts
    unsigned short* q1b  = wB + 786432;
    unsigned short* k1b  = q1b + (size_t)NND;
    unsigned short* v1b  = k1b + (size_t)NND;
    unsigned short* k2b  = v1b + (size_t)NND;                   // 4097 rows
    unsigned short* v2b  = k2b + (size_t)NND + 256;             // 4097 rows

    hipFuncSetAttribute(reinterpret_cast<const void*>(fused_kernel),
                        hipFuncAttributeMaxDynamicSharedMemorySize, SMEM_SZ);

    hipLaunchKernelGGL(prep_kernel, dim3(704), dim3(256), 0, stream,
                       x, memory, active, attn_w, pattn_w, ff_w1, ff_w2, pattn_b,
                       xmB, memB, wB, k2b + (size_t)NND, v2b + (size_t)NND);
    hipLaunchKernelGGL(proj_gemm, dim3(64, 20), dim3(256), 0, stream,
                       xmB, memB, wB, attn_b, pattn_b, q1b, k1b, v1b, k2b, v2b);
    hipLaunchKernelGGL(fused_kernel, dim3(256), dim3(1024), SMEM_SZ, stream,
                       active, x, wB, attn_b, pattn_b, ff_b1, ff_b2, ln_g, ln_b,
                       q1b, k1b, v1b, k2b, v2b, out);
}